// Round 1
// baseline (2229.412 us; speedup 1.0000x reference)
//
#include <hip/hip_runtime.h>
#include <stdint.h>

#define NN 8192
#define DD 512
#define EE 131072
#define BBATCH 16
#define NPG 512
#define SSEL 128
#define LL 3

typedef unsigned short u16;
typedef __bf16 bf16x8 __attribute__((ext_vector_type(8)));
typedef float f32x4 __attribute__((ext_vector_type(4)));
typedef u16 u16x8 __attribute__((ext_vector_type(8)));

__device__ __forceinline__ float bf2f(u16 u) {
    union { unsigned i; float f; } v; v.i = ((unsigned)u) << 16; return v.f;
}
__device__ __forceinline__ u16 f2bf(float f) {
    union { unsigned i; float f; } v; v.f = f;
    unsigned i = v.i;
    return (u16)((i + 0x7FFFu + ((i >> 16) & 1u)) >> 16);  // RNE
}

// ---------------- LayerNorm: fp32 [rows, 512] -> bf16 [rows, 512], wave per row
__global__ __launch_bounds__(64) void ln_kernel(const float* __restrict__ x,
                                                const float* __restrict__ g,
                                                const float* __restrict__ b,
                                                u16* __restrict__ h) {
    int row = blockIdx.x;
    int lane = threadIdx.x;
    const f32x4* x4 = (const f32x4*)(x + (size_t)row * DD);
    f32x4 p = x4[lane * 2], q = x4[lane * 2 + 1];
    float v[8];
    v[0] = p[0]; v[1] = p[1]; v[2] = p[2]; v[3] = p[3];
    v[4] = q[0]; v[5] = q[1]; v[6] = q[2]; v[7] = q[3];
    float s = 0.f, sq = 0.f;
    #pragma unroll
    for (int i = 0; i < 8; ++i) { s += v[i]; sq += v[i] * v[i]; }
    #pragma unroll
    for (int o = 32; o >= 1; o >>= 1) { s += __shfl_xor(s, o); sq += __shfl_xor(sq, o); }
    float mu = s * (1.f / DD);
    float var = sq * (1.f / DD) - mu * mu;
    float rs = rsqrtf(var + 1e-5f);
    int kb = lane * 8;
    u16x8 o8;
    #pragma unroll
    for (int i = 0; i < 8; ++i) o8[i] = f2bf((v[i] - mu) * rs * g[kb + i] + b[kb + i]);
    *(u16x8*)(h + (size_t)row * DD + kb) = o8;
}

// ---------------- counting sort by dst
__global__ void hist_kernel(const int* __restrict__ dst, int* __restrict__ cnt) {
    int e = blockIdx.x * 256 + threadIdx.x;
    if (e < EE) atomicAdd(&cnt[dst[e]], 1);
}

__global__ __launch_bounds__(1024) void scan_kernel(const int* __restrict__ cnt,
                                                    int* __restrict__ off,
                                                    int* __restrict__ cur) {
    __shared__ int part[1024];
    int t = threadIdx.x;
    int base = t * 8;
    int loc[8]; int s = 0;
    #pragma unroll
    for (int i = 0; i < 8; ++i) { loc[i] = s; s += cnt[base + i]; }
    part[t] = s;
    __syncthreads();
    for (int o = 1; o < 1024; o <<= 1) {
        int v = part[t];
        int u = (t >= o) ? part[t - o] : 0;
        __syncthreads();
        part[t] = v + u;
        __syncthreads();
    }
    int bx = (t > 0) ? part[t - 1] : 0;
    #pragma unroll
    for (int i = 0; i < 8; ++i) { off[base + i] = bx + loc[i]; cur[base + i] = bx + loc[i]; }
    if (t == 0) off[NN] = part[1023];
}

__global__ void scatter_kernel(const int* __restrict__ src, const int* __restrict__ dst,
                               int* __restrict__ cur, int* __restrict__ ssrc,
                               int* __restrict__ sdst) {
    int e = blockIdx.x * 256 + threadIdx.x;
    if (e < EE) {
        int d = dst[e];
        int p = atomicAdd(&cur[d], 1);
        ssrc[p] = src[e];
        sdst[p] = d;
    }
}

// ---------------- weight transpose + bf16 cvt: src fp32 [K][Nn] -> dst bf16 [Nn][K]
__global__ void cvt_t_kernel(const float* __restrict__ src, u16* __restrict__ dstp,
                             int K, int Nn) {
    int t = blockIdx.x * 256 + threadIdx.x;
    if (t >= K * Nn) return;
    int n = t / K, k = t - n * K;
    dstp[t] = f2bf(src[(size_t)k * Nn + n]);
}

// ---------------- MFMA GEMM, 128x128 tile, 256 threads (2x2 waves of 64x64)
// AMODE 0: A row r = ef[sorted edge ebase+r] = [h[dst], h[src]-h[dst]]  (KDIM=1024)
// AMODE 1: A = Asrc bf16 [mlen, KDIM]
// EMODE 0: C = relu(acc + bias) -> bf16
// EMODE 1: C = acc + bias + resid -> fp32
template <int AMODE, int KDIM, int EMODE>
__global__ __launch_bounds__(256) void gemm_kernel(
    const u16* __restrict__ Asrc, const int* __restrict__ ssrc,
    const int* __restrict__ sdst, const u16* __restrict__ hsrc,
    const u16* __restrict__ BT, const float* __restrict__ bias,
    const float* __restrict__ resid, void* __restrict__ Cout, int mlen, int ebase) {
    __shared__ u16 lA[128 * 64];
    __shared__ u16 lB[128 * 64];
    const int tid = threadIdx.x;
    const int tileM = blockIdx.x, tileN = blockIdx.y;
    const int lane = tid & 63;
    const int wave = tid >> 6;
    const int wm = wave & 1, wn = wave >> 1;
    const int quad = lane >> 4, lm = lane & 15;

    f32x4 acc[4][4];
    #pragma unroll
    for (int mt = 0; mt < 4; ++mt)
        #pragma unroll
        for (int nt = 0; nt < 4; ++nt)
            #pragma unroll
            for (int j = 0; j < 4; ++j) acc[mt][nt][j] = 0.f;

    for (int kb = 0; kb < KDIM; kb += 64) {
        #pragma unroll
        for (int i = 0; i < 4; ++i) {
            int G = tid + i * 256;          // 0..1023 granules (row, 16B piece)
            int row = G >> 3, gg = G & 7;
            int kg = kb + gg * 8;
            u16x8 av;
            int rr = tileM * 128 + row;
            if (rr >= mlen) rr = 0;
            if (AMODE == 0) {
                int es = ebase + rr;
                int dn = sdst[es], sn = ssrc[es];
                if (kg < 512) {
                    av = *(const u16x8*)(hsrc + (size_t)dn * DD + kg);
                } else {
                    u16x8 aj = *(const u16x8*)(hsrc + (size_t)sn * DD + (kg - 512));
                    u16x8 ai = *(const u16x8*)(hsrc + (size_t)dn * DD + (kg - 512));
                    #pragma unroll
                    for (int j = 0; j < 8; ++j) av[j] = f2bf(bf2f(aj[j]) - bf2f(ai[j]));
                }
            } else {
                av = *(const u16x8*)(Asrc + (size_t)rr * KDIM + kg);
            }
            *(u16x8*)(lA + row * 64 + ((gg ^ (row & 7)) << 3)) = av;
            int nrow = tileN * 128 + row;
            u16x8 bv = *(const u16x8*)(BT + (size_t)nrow * KDIM + kg);
            *(u16x8*)(lB + row * 64 + ((gg ^ (row & 7)) << 3)) = bv;
        }
        __syncthreads();
        #pragma unroll
        for (int kk = 0; kk < 64; kk += 32) {
            bf16x8 af[4], bfr[4];
            int gbase = (kk >> 3) + quad;
            #pragma unroll
            for (int mt = 0; mt < 4; ++mt) {
                int row = wm * 64 + mt * 16 + lm;
                af[mt] = *(const bf16x8*)(lA + row * 64 + ((gbase ^ (row & 7)) << 3));
            }
            #pragma unroll
            for (int nt = 0; nt < 4; ++nt) {
                int row = wn * 64 + nt * 16 + lm;
                bfr[nt] = *(const bf16x8*)(lB + row * 64 + ((gbase ^ (row & 7)) << 3));
            }
            #pragma unroll
            for (int mt = 0; mt < 4; ++mt)
                #pragma unroll
                for (int nt = 0; nt < 4; ++nt)
                    acc[mt][nt] = __builtin_amdgcn_mfma_f32_16x16x32_bf16(
                        af[mt], bfr[nt], acc[mt][nt], 0, 0, 0);
        }
        __syncthreads();
    }
    // epilogue: C row = (lane>>4)*4 + j, col = lane&15  [m89-verified mapping]
    #pragma unroll
    for (int mt = 0; mt < 4; ++mt) {
        #pragma unroll
        for (int nt = 0; nt < 4; ++nt) {
            int col = tileN * 128 + wn * 64 + nt * 16 + lm;
            float bv = bias[col];
            #pragma unroll
            for (int j = 0; j < 4; ++j) {
                int grow = tileM * 128 + wm * 64 + mt * 16 + quad * 4 + j;
                if (grow < mlen) {
                    float v = acc[mt][nt][j] + bv;
                    if (EMODE == 0) {
                        v = fmaxf(v, 0.f);
                        ((u16*)Cout)[(size_t)grow * DD + col] = f2bf(v);
                    } else {
                        v += resid[(size_t)grow * DD + col];
                        ((float*)Cout)[(size_t)grow * DD + col] = v;
                    }
                }
            }
        }
    }
}

// ---------------- segment max over sorted edge rows (one workgroup per node)
__global__ __launch_bounds__(256) void segmax_kernel(const u16* __restrict__ m,
                                                     const int* __restrict__ off,
                                                     float* __restrict__ agg, int e0,
                                                     int e1) {
    int n = blockIdx.x;
    int t = threadIdx.x;
    int lo = off[n], hi = off[n + 1];
    if (lo < e0) lo = e0;
    if (hi > e1) hi = e1;
    if (lo >= hi) return;
    float v0 = agg[(size_t)n * DD + t];
    float v1 = agg[(size_t)n * DD + t + 256];
    for (int e = lo; e < hi; ++e) {
        const u16* mr = m + (size_t)(e - e0) * DD;
        v0 = fmaxf(v0, bf2f(mr[t]));
        v1 = fmaxf(v1, bf2f(mr[t + 256]));
    }
    agg[(size_t)n * DD + t] = v0;
    agg[(size_t)n * DD + t + 256] = v1;
}

// ---------------- x += agg   (agg already >= 0 == relu'd)
__global__ void xupd_kernel(float* __restrict__ x, const float* __restrict__ agg) {
    int i = blockIdx.x * 256 + threadIdx.x;
    f32x4* x4 = (f32x4*)x;
    const f32x4* a4 = (const f32x4*)agg;
    f32x4 r = x4[i];
    f32x4 a = a4[i];
    #pragma unroll
    for (int j = 0; j < 4; ++j) r[j] += a[j];
    x4[i] = r;
}

// ---------------- gather selected rows: xs[i] = x[b*NPG + sel[i]]
__global__ __launch_bounds__(128) void gather_kernel(const float* __restrict__ x,
                                                     const int* __restrict__ sel,
                                                     float* __restrict__ xs) {
    int i = blockIdx.x;          // 0..2047
    int b = i >> 7;              // S = 128
    int r = b * NPG + sel[i];
    const f32x4* srcp = (const f32x4*)(x + (size_t)r * DD);
    f32x4* dstp = (f32x4*)(xs + (size_t)i * DD);
    dstp[threadIdx.x] = srcp[threadIdx.x];
}

extern "C" void kernel_launch(void* const* d_in, const int* in_sizes, int n_in,
                              void* d_out, int out_size, void* d_ws, size_t ws_size,
                              hipStream_t stream) {
    const float* x_in = (const float*)d_in[0];
    const int* ei = (const int*)d_in[1];
    const int* sel = (const int*)d_in[2];
    const float* W1 = (const float*)d_in[4];
    const float* b1 = (const float*)d_in[5];
    const float* W2 = (const float*)d_in[6];
    const float* b2 = (const float*)d_in[7];
    const float* g1 = (const float*)d_in[8];
    const float* be1 = (const float*)d_in[9];
    const float* g2 = (const float*)d_in[10];
    const float* be2 = (const float*)d_in[11];
    const float* fW1 = (const float*)d_in[12];
    const float* fb1 = (const float*)d_in[13];
    const float* fW2 = (const float*)d_in[14];
    const float* fb2 = (const float*)d_in[15];
    float* out = (float*)d_out;

    char* w = (char*)d_ws;
    size_t off = 0;
    auto alloc = [&](size_t bytes) -> char* {
        char* p = w + off;
        off += (bytes + 255) & ~(size_t)255;
        return p;
    };
    float* xbuf = (float*)alloc((size_t)NN * DD * 4);
    float* agg  = (float*)alloc((size_t)NN * DD * 4);
    u16* h      = (u16*)alloc((size_t)NN * DD * 2);
    u16* W1T    = (u16*)alloc((size_t)LL * DD * 1024 * 2);
    u16* W2T    = (u16*)alloc((size_t)LL * DD * DD * 2);
    u16* FW1T   = (u16*)alloc((size_t)DD * DD * 2);
    u16* FW2T   = (u16*)alloc((size_t)DD * DD * 2);
    int* cnt    = (int*)alloc((size_t)NN * 4);
    int* offs   = (int*)alloc((size_t)(NN + 1) * 4);
    int* cur    = (int*)alloc((size_t)NN * 4);
    int* ssrc   = (int*)alloc((size_t)EE * 4);
    int* sdst   = (int*)alloc((size_t)EE * 4);
    float* xs   = (float*)alloc((size_t)BBATCH * SSEL * DD * 4);
    u16* hs     = (u16*)alloc((size_t)BBATCH * SSEL * DD * 2);
    u16* uu     = (u16*)alloc((size_t)BBATCH * SSEL * DD * 2);

    size_t avail = (ws_size > off) ? (ws_size - off) : 0;
    long cap = (long)(avail / (size_t)(2 * DD * 2));  // t + m rows, bf16
    if (cap > EE) cap = EE;
    cap &= ~(long)127;
    if (cap < 128) cap = 128;
    u16* t    = (u16*)alloc((size_t)cap * DD * 2);
    u16* mbuf = (u16*)alloc((size_t)cap * DD * 2);

    const int* esrc = ei;       // edge_index[0] = x_j
    const int* edst = ei + EE;  // edge_index[1] = x_i / aggregation index

    hipMemcpyAsync(xbuf, x_in, (size_t)NN * DD * 4, hipMemcpyDeviceToDevice, stream);
    hipMemsetAsync(cnt, 0, (size_t)NN * 4, stream);
    hist_kernel<<<EE / 256, 256, 0, stream>>>(edst, cnt);
    scan_kernel<<<1, 1024, 0, stream>>>(cnt, offs, cur);
    scatter_kernel<<<EE / 256, 256, 0, stream>>>(esrc, edst, cur, ssrc, sdst);

    for (int l = 0; l < LL; ++l) {
        cvt_t_kernel<<<(1024 * DD + 255) / 256, 256, 0, stream>>>(
            W1 + (size_t)l * 1024 * DD, W1T + (size_t)l * DD * 1024, 1024, DD);
        cvt_t_kernel<<<(DD * DD + 255) / 256, 256, 0, stream>>>(
            W2 + (size_t)l * DD * DD, W2T + (size_t)l * DD * DD, DD, DD);
    }
    cvt_t_kernel<<<(DD * DD + 255) / 256, 256, 0, stream>>>(fW1, FW1T, DD, DD);
    cvt_t_kernel<<<(DD * DD + 255) / 256, 256, 0, stream>>>(fW2, FW2T, DD, DD);

    for (int l = 0; l < LL; ++l) {
        ln_kernel<<<NN, 64, 0, stream>>>(xbuf, g1, be1, h);
        hipMemsetAsync(agg, 0, (size_t)NN * DD * 4, stream);
        for (long e0 = 0; e0 < EE; e0 += cap) {
            int len = (int)(((long)EE - e0 < cap) ? ((long)EE - e0) : cap);
            dim3 grid((len + 127) / 128, 4);
            gemm_kernel<0, 1024, 0><<<grid, 256, 0, stream>>>(
                nullptr, ssrc, sdst, h, W1T + (size_t)l * DD * 1024, b1 + l * DD,
                nullptr, t, len, (int)e0);
            gemm_kernel<1, 512, 0><<<grid, 256, 0, stream>>>(
                t, nullptr, nullptr, nullptr, W2T + (size_t)l * DD * DD, b2 + l * DD,
                nullptr, mbuf, len, 0);
            segmax_kernel<<<NN, 256, 0, stream>>>(mbuf, offs, agg, (int)e0,
                                                  (int)(e0 + len));
        }
        xupd_kernel<<<(NN * DD / 4) / 256, 256, 0, stream>>>(xbuf, agg);
    }

    gather_kernel<<<BBATCH * SSEL, 128, 0, stream>>>(xbuf, sel, xs);
    ln_kernel<<<BBATCH * SSEL, 64, 0, stream>>>(xs, g2, be2, hs);
    dim3 gridf((BBATCH * SSEL + 127) / 128, 4);
    gemm_kernel<1, 512, 0><<<gridf, 256, 0, stream>>>(
        hs, nullptr, nullptr, nullptr, FW1T, fb1, nullptr, uu, BBATCH * SSEL, 0);
    gemm_kernel<1, 512, 1><<<gridf, 256, 0, stream>>>(
        uu, nullptr, nullptr, nullptr, FW2T, fb2, xs, out, BBATCH * SSEL, 0);
}

// Round 2
// 944.965 us; speedup vs baseline: 2.3593x; 2.3593x over previous
//
#include <hip/hip_runtime.h>
#include <stdint.h>

#define NN 8192
#define DD 512
#define EE 131072
#define BBATCH 16
#define NPG 512
#define SSEL 128
#define LL 3

typedef unsigned short u16;
typedef __bf16 bf16x8 __attribute__((ext_vector_type(8)));
typedef float f32x4 __attribute__((ext_vector_type(4)));
typedef u16 u16x8 __attribute__((ext_vector_type(8)));

__device__ __forceinline__ float bf2f(u16 u) {
    union { unsigned i; float f; } v; v.i = ((unsigned)u) << 16; return v.f;
}
__device__ __forceinline__ u16 f2bf(float f) {
    union { unsigned i; float f; } v; v.f = f;
    unsigned i = v.i;
    return (u16)((i + 0x7FFFu + ((i >> 16) & 1u)) >> 16);  // RNE
}

// async global->LDS, 16B per lane, LDS dest = wave-uniform base + lane*16
__device__ __forceinline__ void async_cp16(const u16* g, u16* l) {
    __builtin_amdgcn_global_load_lds(
        (const __attribute__((address_space(1))) unsigned int*)g,
        (__attribute__((address_space(3))) unsigned int*)l, 16, 0, 0);
}

// ---------------- LayerNorm: fp32 [rows, 512] -> bf16 [rows, 512], wave per row
__global__ __launch_bounds__(64) void ln_kernel(const float* __restrict__ x,
                                                const float* __restrict__ g,
                                                const float* __restrict__ b,
                                                u16* __restrict__ h) {
    int row = blockIdx.x;
    int lane = threadIdx.x;
    const f32x4* x4 = (const f32x4*)(x + (size_t)row * DD);
    f32x4 p = x4[lane * 2], q = x4[lane * 2 + 1];
    float v[8];
    v[0] = p[0]; v[1] = p[1]; v[2] = p[2]; v[3] = p[3];
    v[4] = q[0]; v[5] = q[1]; v[6] = q[2]; v[7] = q[3];
    float s = 0.f, sq = 0.f;
    #pragma unroll
    for (int i = 0; i < 8; ++i) { s += v[i]; sq += v[i] * v[i]; }
    #pragma unroll
    for (int o = 32; o >= 1; o >>= 1) { s += __shfl_xor(s, o); sq += __shfl_xor(sq, o); }
    float mu = s * (1.f / DD);
    float var = sq * (1.f / DD) - mu * mu;
    float rs = rsqrtf(var + 1e-5f);
    int kb = lane * 8;
    u16x8 o8;
    #pragma unroll
    for (int i = 0; i < 8; ++i) o8[i] = f2bf((v[i] - mu) * rs * g[kb + i] + b[kb + i]);
    *(u16x8*)(h + (size_t)row * DD + kb) = o8;
}

// ---------------- counting sort by dst
__global__ void hist_kernel(const int* __restrict__ dst, int* __restrict__ cnt) {
    int e = blockIdx.x * 256 + threadIdx.x;
    if (e < EE) atomicAdd(&cnt[dst[e]], 1);
}

__global__ __launch_bounds__(1024) void scan_kernel(const int* __restrict__ cnt,
                                                    int* __restrict__ off,
                                                    int* __restrict__ cur) {
    __shared__ int part[1024];
    int t = threadIdx.x;
    int base = t * 8;
    int loc[8]; int s = 0;
    #pragma unroll
    for (int i = 0; i < 8; ++i) { loc[i] = s; s += cnt[base + i]; }
    part[t] = s;
    __syncthreads();
    for (int o = 1; o < 1024; o <<= 1) {
        int v = part[t];
        int u = (t >= o) ? part[t - o] : 0;
        __syncthreads();
        part[t] = v + u;
        __syncthreads();
    }
    int bx = (t > 0) ? part[t - 1] : 0;
    #pragma unroll
    for (int i = 0; i < 8; ++i) { off[base + i] = bx + loc[i]; cur[base + i] = bx + loc[i]; }
    if (t == 0) off[NN] = part[1023];
}

__global__ void scatter_kernel(const int* __restrict__ src, const int* __restrict__ dst,
                               int* __restrict__ cur, int* __restrict__ ssrc,
                               int* __restrict__ sdst) {
    int e = blockIdx.x * 256 + threadIdx.x;
    if (e < EE) {
        int d = dst[e];
        int p = atomicAdd(&cur[d], 1);
        ssrc[p] = src[e];
        sdst[p] = d;
    }
}

// ---------------- weight transpose + bf16 cvt: src fp32 [K][Nn] -> dst bf16 [Nn][K]
__global__ void cvt_t_kernel(const float* __restrict__ src, u16* __restrict__ dstp,
                             int K, int Nn) {
    int t = blockIdx.x * 256 + threadIdx.x;
    if (t >= K * Nn) return;
    int n = t / K, k = t - n * K;
    dstp[t] = f2bf(src[(size_t)k * Nn + n]);
}

// W1 fp32 [1024][512] -> Wcat^T bf16 [1024 rows][512]:
// rows 0..511  = W1a^T (W1[k][n] - W1[512+k][n]); rows 512..1023 = W1b^T (W1[512+k][n-512])
__global__ void cvt_w1_kernel(const float* __restrict__ W1, u16* __restrict__ dstp) {
    int t = blockIdx.x * 256 + threadIdx.x;
    if (t >= 1024 * 512) return;
    int n = t >> 9, k = t & 511;
    float v;
    if (n < 512)
        v = W1[(size_t)k * 512 + n] - W1[(size_t)(k + 512) * 512 + n];
    else
        v = W1[(size_t)(k + 512) * 512 + (n - 512)];
    dstp[t] = f2bf(v);
}

// ---------------- async MFMA GEMM, 128x128 tile, 256 threads (2x2 waves)
// A bf16 [M,K] row-major; BT bf16 [N rows][K]; K multiple of 64; M,N mult of 128.
// EMODE 0: relu(acc+bias) -> bf16 (ldc stride)
// EMODE 1: acc+bias+resid -> fp32
// EMODE 2: acc -> bf16 (no bias)
template <int EMODE>
__global__ __launch_bounds__(256) void gemm_async(
    const u16* __restrict__ A, const u16* __restrict__ BT,
    const float* __restrict__ bias, const float* __restrict__ resid,
    void* __restrict__ Cout, int K, int ldc) {
    __shared__ u16 lA[128 * 64];
    __shared__ u16 lB[128 * 64];
    const int tid = threadIdx.x;
    const int lane = tid & 63, wave = tid >> 6;
    const int wm = wave & 1, wn = wave >> 1;
    const int quad = lane >> 4, lm = lane & 15;
    const int tileM = blockIdx.x, tileN = blockIdx.y;

    // lane's fixed granule permutation: LDS slot (l&7) of row-sub (l>>3) holds
    // global granule g = (l&7)^(l>>3)  -> frag reads at slot g^(row&7) are conflict-free
    const int g = (lane & 7) ^ (lane >> 3);
    const u16* ap[4];
    const u16* bp[4];
    u16* lad[4];
    u16* lbd[4];
    #pragma unroll
    for (int j = 0; j < 4; ++j) {
        int seg = wave * 4 + j;  // 0..15, each = 8 rows = 1KB of LDS
        int rA = tileM * 128 + seg * 8 + (lane >> 3);
        int rB = tileN * 128 + seg * 8 + (lane >> 3);
        ap[j] = A + (size_t)rA * K + g * 8;
        bp[j] = BT + (size_t)rB * K + g * 8;
        lad[j] = lA + seg * 512;
        lbd[j] = lB + seg * 512;
    }

    f32x4 acc[4][4];
    #pragma unroll
    for (int mt = 0; mt < 4; ++mt)
        #pragma unroll
        for (int nt = 0; nt < 4; ++nt)
            #pragma unroll
            for (int j = 0; j < 4; ++j) acc[mt][nt][j] = 0.f;

    for (int kb = 0; kb < K; kb += 64) {
        #pragma unroll
        for (int j = 0; j < 4; ++j) {
            async_cp16(ap[j], lad[j]);
            async_cp16(bp[j], lbd[j]);
            ap[j] += 64;
            bp[j] += 64;
        }
        __syncthreads();
        #pragma unroll
        for (int kk = 0; kk < 64; kk += 32) {
            bf16x8 af[4], bfr[4];
            int gbase = (kk >> 3) + quad;
            #pragma unroll
            for (int mt = 0; mt < 4; ++mt) {
                int row = wm * 64 + mt * 16 + lm;
                af[mt] = *(const bf16x8*)(lA + row * 64 + ((gbase ^ (row & 7)) << 3));
            }
            #pragma unroll
            for (int nt = 0; nt < 4; ++nt) {
                int row = wn * 64 + nt * 16 + lm;
                bfr[nt] = *(const bf16x8*)(lB + row * 64 + ((gbase ^ (row & 7)) << 3));
            }
            #pragma unroll
            for (int mt = 0; mt < 4; ++mt)
                #pragma unroll
                for (int nt = 0; nt < 4; ++nt)
                    acc[mt][nt] = __builtin_amdgcn_mfma_f32_16x16x32_bf16(
                        af[mt], bfr[nt], acc[mt][nt], 0, 0, 0);
        }
        __syncthreads();
    }
    // epilogue: C row = (lane>>4)*4 + j, col = lane&15  [m89-verified mapping]
    #pragma unroll
    for (int mt = 0; mt < 4; ++mt) {
        #pragma unroll
        for (int nt = 0; nt < 4; ++nt) {
            int col = tileN * 128 + wn * 64 + nt * 16 + lm;
            float bv = (EMODE == 2) ? 0.f : bias[col];
            #pragma unroll
            for (int j = 0; j < 4; ++j) {
                int grow = tileM * 128 + wm * 64 + mt * 16 + quad * 4 + j;
                float v = acc[mt][nt][j] + bv;
                if (EMODE == 0) {
                    ((u16*)Cout)[(size_t)grow * ldc + col] = f2bf(fmaxf(v, 0.f));
                } else if (EMODE == 1) {
                    ((float*)Cout)[(size_t)grow * ldc + col] =
                        v + resid[(size_t)grow * ldc + col];
                } else {
                    ((u16*)Cout)[(size_t)grow * ldc + col] = f2bf(v);
                }
            }
        }
    }
}

// ---------------- edge combine: t[idx] = relu(Pa[dst] + Pb[src] + b1), wave/edge
__global__ __launch_bounds__(256) void edge_kernel(const u16* __restrict__ P,
                                                   const int* __restrict__ ssrc,
                                                   const int* __restrict__ sdst,
                                                   const float* __restrict__ b1,
                                                   u16* __restrict__ t, int e0) {
    int idx = blockIdx.x * 4 + (threadIdx.x >> 6);
    int lane = threadIdx.x & 63;
    int e = e0 + idx;
    int dn = sdst[e], sn = ssrc[e];
    u16x8 pa = *(const u16x8*)(P + (size_t)dn * 1024 + lane * 8);
    u16x8 pb = *(const u16x8*)(P + (size_t)sn * 1024 + 512 + lane * 8);
    const f32x4* b4 = (const f32x4*)b1;
    f32x4 bb0 = b4[lane * 2], bb1 = b4[lane * 2 + 1];
    u16x8 o;
    #pragma unroll
    for (int j = 0; j < 4; ++j)
        o[j] = f2bf(fmaxf(bf2f(pa[j]) + bf2f(pb[j]) + bb0[j], 0.f));
    #pragma unroll
    for (int j = 0; j < 4; ++j)
        o[4 + j] = f2bf(fmaxf(bf2f(pa[4 + j]) + bf2f(pb[4 + j]) + bb1[j], 0.f));
    *(u16x8*)(t + (size_t)idx * DD + lane * 8) = o;
}

// ---------------- segment max over sorted edge rows (one workgroup per node)
__global__ __launch_bounds__(256) void segmax_kernel(const u16* __restrict__ m,
                                                     const int* __restrict__ off,
                                                     float* __restrict__ agg, int e0,
                                                     int e1) {
    int n = blockIdx.x;
    int t = threadIdx.x;
    int lo = off[n], hi = off[n + 1];
    if (lo < e0) lo = e0;
    if (hi > e1) hi = e1;
    if (lo >= hi) return;
    float v0 = agg[(size_t)n * DD + t];
    float v1 = agg[(size_t)n * DD + t + 256];
    for (int e = lo; e < hi; ++e) {
        const u16* mr = m + (size_t)(e - e0) * DD;
        v0 = fmaxf(v0, bf2f(mr[t]));
        v1 = fmaxf(v1, bf2f(mr[t + 256]));
    }
    agg[(size_t)n * DD + t] = v0;
    agg[(size_t)n * DD + t + 256] = v1;
}

// ---------------- x += agg   (agg already >= 0 == relu'd)
__global__ void xupd_kernel(float* __restrict__ x, const float* __restrict__ agg) {
    int i = blockIdx.x * 256 + threadIdx.x;
    f32x4* x4 = (f32x4*)x;
    const f32x4* a4 = (const f32x4*)agg;
    f32x4 r = x4[i];
    f32x4 a = a4[i];
    #pragma unroll
    for (int j = 0; j < 4; ++j) r[j] += a[j];
    x4[i] = r;
}

// ---------------- gather selected rows: xs[i] = x[b*NPG + sel[i]]
__global__ __launch_bounds__(128) void gather_kernel(const float* __restrict__ x,
                                                     const int* __restrict__ sel,
                                                     float* __restrict__ xs) {
    int i = blockIdx.x;
    int b = i >> 7;
    int r = b * NPG + sel[i];
    const f32x4* srcp = (const f32x4*)(x + (size_t)r * DD);
    f32x4* dstp = (f32x4*)(xs + (size_t)i * DD);
    dstp[threadIdx.x] = srcp[threadIdx.x];
}

extern "C" void kernel_launch(void* const* d_in, const int* in_sizes, int n_in,
                              void* d_out, int out_size, void* d_ws, size_t ws_size,
                              hipStream_t stream) {
    const float* x_in = (const float*)d_in[0];
    const int* ei = (const int*)d_in[1];
    const int* sel = (const int*)d_in[2];
    const float* W1 = (const float*)d_in[4];
    const float* b1 = (const float*)d_in[5];
    const float* W2 = (const float*)d_in[6];
    const float* b2 = (const float*)d_in[7];
    const float* g1 = (const float*)d_in[8];
    const float* be1 = (const float*)d_in[9];
    const float* g2 = (const float*)d_in[10];
    const float* be2 = (const float*)d_in[11];
    const float* fW1 = (const float*)d_in[12];
    const float* fb1 = (const float*)d_in[13];
    const float* fW2 = (const float*)d_in[14];
    const float* fb2 = (const float*)d_in[15];
    float* out = (float*)d_out;

    char* w = (char*)d_ws;
    size_t off = 0;
    auto alloc = [&](size_t bytes) -> char* {
        char* p = w + off;
        off += (bytes + 255) & ~(size_t)255;
        return p;
    };
    float* xbuf = (float*)alloc((size_t)NN * DD * 4);
    float* agg  = (float*)alloc((size_t)NN * DD * 4);
    u16* h      = (u16*)alloc((size_t)NN * DD * 2);
    u16* P      = (u16*)alloc((size_t)NN * 1024 * 2);
    u16* W1T    = (u16*)alloc((size_t)LL * 1024 * DD * 2);  // [1024 rows][512] per layer
    u16* W2T    = (u16*)alloc((size_t)LL * DD * DD * 2);
    u16* FW1T   = (u16*)alloc((size_t)DD * DD * 2);
    u16* FW2T   = (u16*)alloc((size_t)DD * DD * 2);
    int* cnt    = (int*)alloc((size_t)NN * 4);
    int* offs   = (int*)alloc((size_t)(NN + 1) * 4);
    int* cur    = (int*)alloc((size_t)NN * 4);
    int* ssrc   = (int*)alloc((size_t)EE * 4);
    int* sdst   = (int*)alloc((size_t)EE * 4);
    float* xs   = (float*)alloc((size_t)BBATCH * SSEL * DD * 4);
    u16* hs     = (u16*)alloc((size_t)BBATCH * SSEL * DD * 2);
    u16* uu     = (u16*)alloc((size_t)BBATCH * SSEL * DD * 2);

    size_t avail = (ws_size > off) ? (ws_size - off) : 0;
    long cap = (long)(avail / (size_t)(2 * DD * 2));  // t + m rows, bf16
    if (cap > EE) cap = EE;
    cap &= ~(long)127;
    if (cap < 128) cap = 128;
    u16* t    = (u16*)alloc((size_t)cap * DD * 2);
    u16* mbuf = (u16*)alloc((size_t)cap * DD * 2);

    const int* esrc = ei;       // edge_index[0] = x_j
    const int* edst = ei + EE;  // edge_index[1] = x_i / aggregation index

    hipMemcpyAsync(xbuf, x_in, (size_t)NN * DD * 4, hipMemcpyDeviceToDevice, stream);
    hipMemsetAsync(cnt, 0, (size_t)NN * 4, stream);
    hist_kernel<<<EE / 256, 256, 0, stream>>>(edst, cnt);
    scan_kernel<<<1, 1024, 0, stream>>>(cnt, offs, cur);
    scatter_kernel<<<EE / 256, 256, 0, stream>>>(esrc, edst, cur, ssrc, sdst);

    for (int l = 0; l < LL; ++l) {
        cvt_w1_kernel<<<(1024 * DD + 255) / 256, 256, 0, stream>>>(
            W1 + (size_t)l * 1024 * DD, W1T + (size_t)l * 1024 * DD);
        cvt_t_kernel<<<(DD * DD + 255) / 256, 256, 0, stream>>>(
            W2 + (size_t)l * DD * DD, W2T + (size_t)l * DD * DD, DD, DD);
    }
    cvt_t_kernel<<<(DD * DD + 255) / 256, 256, 0, stream>>>(fW1, FW1T, DD, DD);
    cvt_t_kernel<<<(DD * DD + 255) / 256, 256, 0, stream>>>(fW2, FW2T, DD, DD);

    for (int l = 0; l < LL; ++l) {
        ln_kernel<<<NN, 64, 0, stream>>>(xbuf, g1, be1, h);
        // P = h @ [W1a | W1b]   [8192 x 1024] bf16
        {
            dim3 grid(NN / 128, 1024 / 128);
            gemm_async<2><<<grid, 256, 0, stream>>>(
                h, W1T + (size_t)l * 1024 * DD, nullptr, nullptr, P, DD, 1024);
        }
        hipMemsetAsync(agg, 0, (size_t)NN * DD * 4, stream);
        for (long e0 = 0; e0 < EE; e0 += cap) {
            int len = (int)(((long)EE - e0 < cap) ? ((long)EE - e0) : cap);
            edge_kernel<<<len / 4, 256, 0, stream>>>(P, ssrc, sdst, b1 + l * DD, t,
                                                     (int)e0);
            dim3 grid(len / 128, DD / 128);
            gemm_async<0><<<grid, 256, 0, stream>>>(
                t, W2T + (size_t)l * DD * DD, b2 + (size_t)l * DD, nullptr, mbuf, DD,
                DD);
            segmax_kernel<<<NN, 256, 0, stream>>>(mbuf, offs, agg, (int)e0,
                                                  (int)(e0 + len));
        }
        xupd_kernel<<<(NN * DD / 4) / 256, 256, 0, stream>>>(xbuf, agg);
    }

    gather_kernel<<<BBATCH * SSEL, 128, 0, stream>>>(xbuf, sel, xs);
    ln_kernel<<<BBATCH * SSEL, 64, 0, stream>>>(xs, g2, be2, hs);
    dim3 gridf(BBATCH * SSEL / 128, DD / 128);
    gemm_async<0><<<gridf, 256, 0, stream>>>(hs, FW1T, fb1, nullptr, uu, DD, DD);
    gemm_async<1><<<gridf, 256, 0, stream>>>(uu, FW2T, fb2, xs, out, DD, DD);
}

// Round 3
// 793.103 us; speedup vs baseline: 2.8110x; 1.1915x over previous
//
#include <hip/hip_runtime.h>
#include <stdint.h>

#define NN 8192
#define DD 512
#define EE 131072
#define BBATCH 16
#define NPG 512
#define SSEL 128
#define LL 3

typedef unsigned short u16;
typedef __bf16 bf16x8 __attribute__((ext_vector_type(8)));
typedef float f32x4 __attribute__((ext_vector_type(4)));
typedef u16 u16x8 __attribute__((ext_vector_type(8)));

__device__ __forceinline__ float bf2f(u16 u) {
    union { unsigned i; float f; } v; v.i = ((unsigned)u) << 16; return v.f;
}
__device__ __forceinline__ u16 f2bf(float f) {
    union { unsigned i; float f; } v; v.f = f;
    unsigned i = v.i;
    return (u16)((i + 0x7FFFu + ((i >> 16) & 1u)) >> 16);  // RNE
}

// async global->LDS, 16B per lane, LDS dest = wave-uniform base + lane*16
__device__ __forceinline__ void async_cp16(const u16* g, u16* l) {
    __builtin_amdgcn_global_load_lds(
        (const __attribute__((address_space(1))) unsigned int*)g,
        (__attribute__((address_space(3))) unsigned int*)l, 16, 0, 0);
}

// ---------------- LayerNorm (+ optional residual-add + agg zeroing)
// xnew = doAdd ? xin + agg : xin ;  h = bf16(LN(xnew)) ; xout = xnew ; agg = 0
__global__ __launch_bounds__(64) void ln_fused(const float* __restrict__ xin,
                                               float* __restrict__ agg_io,
                                               float* __restrict__ xout,
                                               const float* __restrict__ g,
                                               const float* __restrict__ b,
                                               u16* __restrict__ h, int doAdd) {
    int row = blockIdx.x;
    int lane = threadIdx.x;
    const f32x4* x4 = (const f32x4*)(xin + (size_t)row * DD);
    f32x4 p = x4[lane * 2], q = x4[lane * 2 + 1];
    if (doAdd) {
        const f32x4* a4 = (const f32x4*)(agg_io + (size_t)row * DD);
        f32x4 pa = a4[lane * 2], qa = a4[lane * 2 + 1];
        #pragma unroll
        for (int i = 0; i < 4; ++i) { p[i] += pa[i]; q[i] += qa[i]; }
    }
    if (agg_io) {
        f32x4 z;
        #pragma unroll
        for (int i = 0; i < 4; ++i) z[i] = 0.f;
        f32x4* a4 = (f32x4*)(agg_io + (size_t)row * DD);
        a4[lane * 2] = z;
        a4[lane * 2 + 1] = z;
    }
    f32x4* xo = (f32x4*)(xout + (size_t)row * DD);
    xo[lane * 2] = p;
    xo[lane * 2 + 1] = q;
    float v[8];
    v[0] = p[0]; v[1] = p[1]; v[2] = p[2]; v[3] = p[3];
    v[4] = q[0]; v[5] = q[1]; v[6] = q[2]; v[7] = q[3];
    float s = 0.f, sq = 0.f;
    #pragma unroll
    for (int i = 0; i < 8; ++i) { s += v[i]; sq += v[i] * v[i]; }
    #pragma unroll
    for (int o = 32; o >= 1; o >>= 1) { s += __shfl_xor(s, o); sq += __shfl_xor(sq, o); }
    float mu = s * (1.f / DD);
    float var = sq * (1.f / DD) - mu * mu;
    float rs = rsqrtf(var + 1e-5f);
    int kb = lane * 8;
    u16x8 o8;
    #pragma unroll
    for (int i = 0; i < 8; ++i) o8[i] = f2bf((v[i] - mu) * rs * g[kb + i] + b[kb + i]);
    *(u16x8*)(h + (size_t)row * DD + kb) = o8;
}

// ---------------- counting sort by dst
__global__ void hist_kernel(const int* __restrict__ dst, int* __restrict__ cnt) {
    int e = blockIdx.x * 256 + threadIdx.x;
    if (e < EE) atomicAdd(&cnt[dst[e]], 1);
}

__global__ __launch_bounds__(1024) void scan_kernel(const int* __restrict__ cnt,
                                                    int* __restrict__ off,
                                                    int* __restrict__ cur) {
    __shared__ int part[1024];
    int t = threadIdx.x;
    int base = t * 8;
    int loc[8]; int s = 0;
    #pragma unroll
    for (int i = 0; i < 8; ++i) { loc[i] = s; s += cnt[base + i]; }
    part[t] = s;
    __syncthreads();
    for (int o = 1; o < 1024; o <<= 1) {
        int v = part[t];
        int u = (t >= o) ? part[t - o] : 0;
        __syncthreads();
        part[t] = v + u;
        __syncthreads();
    }
    int bx = (t > 0) ? part[t - 1] : 0;
    #pragma unroll
    for (int i = 0; i < 8; ++i) { off[base + i] = bx + loc[i]; cur[base + i] = bx + loc[i]; }
    if (t == 0) off[NN] = part[1023];
}

__global__ void scatter_kernel(const int* __restrict__ src, const int* __restrict__ dst,
                               int* __restrict__ cur, int* __restrict__ ssrc,
                               int* __restrict__ sdst) {
    int e = blockIdx.x * 256 + threadIdx.x;
    if (e < EE) {
        int d = dst[e];
        int p = atomicAdd(&cur[d], 1);
        ssrc[p] = src[e];
        sdst[p] = d;
    }
}

// ---------------- weight transpose + bf16 cvt: src fp32 [K][Nn] -> dst bf16 [Nn][K]
__global__ void cvt_t_kernel(const float* __restrict__ src, u16* __restrict__ dstp,
                             int K, int Nn) {
    int t = blockIdx.x * 256 + threadIdx.x;
    if (t >= K * Nn) return;
    int n = t / K, k = t - n * K;
    dstp[t] = f2bf(src[(size_t)k * Nn + n]);
}

// W1 fp32 [1024][512] -> Wcat^T bf16 [1024 rows][512]:
// rows 0..511  = (W1a - W1b)^T ; rows 512..1023 = W1b^T
__global__ void cvt_w1_kernel(const float* __restrict__ W1, u16* __restrict__ dstp) {
    int t = blockIdx.x * 256 + threadIdx.x;
    if (t >= 1024 * 512) return;
    int n = t >> 9, k = t & 511;
    float v;
    if (n < 512)
        v = W1[(size_t)k * 512 + n] - W1[(size_t)(k + 512) * 512 + n];
    else
        v = W1[(size_t)(k + 512) * 512 + (n - 512)];
    dstp[t] = f2bf(v);
}

// ---------------- async MFMA GEMM, 128x128 tile, 256 threads (2x2 waves)
// EMODE 0: relu(acc+bias) -> bf16 ; EMODE 1: acc+bias+resid -> fp32 ; EMODE 2: acc -> bf16
template <int EMODE>
__global__ __launch_bounds__(256) void gemm_async(
    const u16* __restrict__ A, const u16* __restrict__ BT,
    const float* __restrict__ bias, const float* __restrict__ resid,
    void* __restrict__ Cout, int K, int ldc) {
    __shared__ u16 lA[128 * 64];
    __shared__ u16 lB[128 * 64];
    const int tid = threadIdx.x;
    const int lane = tid & 63, wave = tid >> 6;
    const int wm = wave & 1, wn = wave >> 1;
    const int quad = lane >> 4, lm = lane & 15;
    const int tileM = blockIdx.x, tileN = blockIdx.y;

    const int g = (lane & 7) ^ (lane >> 3);
    const u16* ap[4];
    const u16* bp[4];
    u16* lad[4];
    u16* lbd[4];
    #pragma unroll
    for (int j = 0; j < 4; ++j) {
        int seg = wave * 4 + j;
        int rA = tileM * 128 + seg * 8 + (lane >> 3);
        int rB = tileN * 128 + seg * 8 + (lane >> 3);
        ap[j] = A + (size_t)rA * K + g * 8;
        bp[j] = BT + (size_t)rB * K + g * 8;
        lad[j] = lA + seg * 512;
        lbd[j] = lB + seg * 512;
    }

    f32x4 acc[4][4];
    #pragma unroll
    for (int mt = 0; mt < 4; ++mt)
        #pragma unroll
        for (int nt = 0; nt < 4; ++nt)
            #pragma unroll
            for (int j = 0; j < 4; ++j) acc[mt][nt][j] = 0.f;

    for (int kb = 0; kb < K; kb += 64) {
        #pragma unroll
        for (int j = 0; j < 4; ++j) {
            async_cp16(ap[j], lad[j]);
            async_cp16(bp[j], lbd[j]);
            ap[j] += 64;
            bp[j] += 64;
        }
        __syncthreads();
        #pragma unroll
        for (int kk = 0; kk < 64; kk += 32) {
            bf16x8 af[4], bfr[4];
            int gbase = (kk >> 3) + quad;
            #pragma unroll
            for (int mt = 0; mt < 4; ++mt) {
                int row = wm * 64 + mt * 16 + lm;
                af[mt] = *(const bf16x8*)(lA + row * 64 + ((gbase ^ (row & 7)) << 3));
            }
            #pragma unroll
            for (int nt = 0; nt < 4; ++nt) {
                int row = wn * 64 + nt * 16 + lm;
                bfr[nt] = *(const bf16x8*)(lB + row * 64 + ((gbase ^ (row & 7)) << 3));
            }
            #pragma unroll
            for (int mt = 0; mt < 4; ++mt)
                #pragma unroll
                for (int nt = 0; nt < 4; ++nt)
                    acc[mt][nt] = __builtin_amdgcn_mfma_f32_16x16x32_bf16(
                        af[mt], bfr[nt], acc[mt][nt], 0, 0, 0);
        }
        __syncthreads();
    }
    #pragma unroll
    for (int mt = 0; mt < 4; ++mt) {
        #pragma unroll
        for (int nt = 0; nt < 4; ++nt) {
            int col = tileN * 128 + wn * 64 + nt * 16 + lm;
            float bv = (EMODE == 2) ? 0.f : bias[col];
            #pragma unroll
            for (int j = 0; j < 4; ++j) {
                int grow = tileM * 128 + wm * 64 + mt * 16 + quad * 4 + j;
                float v = acc[mt][nt][j] + bv;
                if (EMODE == 0) {
                    ((u16*)Cout)[(size_t)grow * ldc + col] = f2bf(fmaxf(v, 0.f));
                } else if (EMODE == 1) {
                    ((float*)Cout)[(size_t)grow * ldc + col] =
                        v + resid[(size_t)grow * ldc + col];
                } else {
                    ((u16*)Cout)[(size_t)grow * ldc + col] = f2bf(v);
                }
            }
        }
    }
}

// ---------------- fused edge GEMM: A = relu(Pa[dst]+Pb[src]+b1) built in staging,
// B = W2T async, epilogue = relu(+b2) -> LDS -> per-node segmax -> atomicMax(agg).
// Tile 128 edges x 256 cols, 512 threads (2x4 waves), grid (EE/128, 2).
__global__ __launch_bounds__(512) void gemm_edge(
    const u16* __restrict__ P, const int* __restrict__ ssrc,
    const int* __restrict__ sdst, const u16* __restrict__ W2T,
    const float* __restrict__ b1, const float* __restrict__ b2,
    float* __restrict__ agg) {
    __shared__ u16 smem[32768];  // 64KB: lA(16K)+lB(32K) during K-loop; cbuf(64K) epilogue
    __shared__ int nid_l[128], src_l[128];
    u16* lA = smem;             // 128 rows x 64 u16
    u16* lB = smem + 8192;      // 256 rows x 64 u16
    const int tid = threadIdx.x;
    const int lane = tid & 63, wave = tid >> 6;  // 8 waves
    const int wm = wave & 1, wn = wave >> 1;     // 2 x 4
    const int quad = lane >> 4, lm = lane & 15;
    const int tileM = blockIdx.x, tileN = blockIdx.y;
    const int ebase = tileM * 128;

    if (tid < 128) {
        nid_l[tid] = sdst[ebase + tid];
        src_l[tid] = ssrc[ebase + tid];
    }
    __syncthreads();

    const int g = (lane & 7) ^ (lane >> 3);
    // A register staging: 2 segments of 8 rows per wave
    const u16* pap[2];
    const u16* pbp[2];
    u16* lout[2];
    #pragma unroll
    for (int j = 0; j < 2; ++j) {
        int seg = wave * 2 + j;
        int row = seg * 8 + (lane >> 3);
        int dn = nid_l[row], sn = src_l[row];
        pap[j] = P + (size_t)dn * 1024 + g * 8;
        pbp[j] = P + (size_t)sn * 1024 + 512 + g * 8;
        lout[j] = lA + seg * 512 + lane * 8;  // == row*64 + (g^(row&7))*8
    }
    // B async staging: 4 segments per wave (256 rows total)
    const u16* bp[4];
    u16* lbd[4];
    #pragma unroll
    for (int j = 0; j < 4; ++j) {
        int seg = wave * 4 + j;
        int row = tileN * 256 + seg * 8 + (lane >> 3);
        bp[j] = W2T + (size_t)row * 512 + g * 8;
        lbd[j] = lB + seg * 512;
    }
    const float* b1g = b1 + g * 8;

    f32x4 acc[4][4];
    #pragma unroll
    for (int mt = 0; mt < 4; ++mt)
        #pragma unroll
        for (int nt = 0; nt < 4; ++nt)
            #pragma unroll
            for (int j = 0; j < 4; ++j) acc[mt][nt][j] = 0.f;

    for (int kb = 0; kb < 512; kb += 64) {
        #pragma unroll
        for (int j = 0; j < 4; ++j) { async_cp16(bp[j], lbd[j]); bp[j] += 64; }
        f32x4 bb0 = *(const f32x4*)(b1g + kb);
        f32x4 bb1 = *(const f32x4*)(b1g + kb + 4);
        #pragma unroll
        for (int j = 0; j < 2; ++j) {
            u16x8 pa = *(const u16x8*)pap[j];
            u16x8 pb = *(const u16x8*)pbp[j];
            pap[j] += 64;
            pbp[j] += 64;
            u16x8 o;
            #pragma unroll
            for (int q = 0; q < 4; ++q)
                o[q] = f2bf(fmaxf(bf2f(pa[q]) + bf2f(pb[q]) + bb0[q], 0.f));
            #pragma unroll
            for (int q = 0; q < 4; ++q)
                o[4 + q] = f2bf(fmaxf(bf2f(pa[4 + q]) + bf2f(pb[4 + q]) + bb1[q], 0.f));
            *(u16x8*)lout[j] = o;
        }
        __syncthreads();
        #pragma unroll
        for (int kk = 0; kk < 64; kk += 32) {
            bf16x8 af[4], bfr[4];
            int gbase = (kk >> 3) + quad;
            #pragma unroll
            for (int mt = 0; mt < 4; ++mt) {
                int row = wm * 64 + mt * 16 + lm;
                af[mt] = *(const bf16x8*)(lA + row * 64 + ((gbase ^ (row & 7)) << 3));
            }
            #pragma unroll
            for (int nt = 0; nt < 4; ++nt) {
                int row = wn * 64 + nt * 16 + lm;
                bfr[nt] = *(const bf16x8*)(lB + row * 64 + ((gbase ^ (row & 7)) << 3));
            }
            #pragma unroll
            for (int mt = 0; mt < 4; ++mt)
                #pragma unroll
                for (int nt = 0; nt < 4; ++nt)
                    acc[mt][nt] = __builtin_amdgcn_mfma_f32_16x16x32_bf16(
                        af[mt], bfr[nt], acc[mt][nt], 0, 0, 0);
        }
        __syncthreads();
    }

    // epilogue: relu(acc + b2) -> cbuf (aliases lA/lB; safe after final barrier)
    u16* cbuf = smem;  // [128 rows][256 cols] bf16
    #pragma unroll
    for (int nt = 0; nt < 4; ++nt) {
        int col = wn * 64 + nt * 16 + lm;
        float bv = b2[tileN * 256 + col];
        #pragma unroll
        for (int mt = 0; mt < 4; ++mt) {
            #pragma unroll
            for (int j = 0; j < 4; ++j) {
                int row = wm * 64 + mt * 16 + quad * 4 + j;
                cbuf[row * 256 + col] = f2bf(fmaxf(acc[mt][nt][j] + bv, 0.f));
            }
        }
    }
    __syncthreads();

    // segmax walk: thread -> one col, half of rows; dst-sorted so runs are contiguous.
    // values >= 0 and agg zero-init => uint atomicMax == float max.
    {
        int col = tid & 255;
        int gcol = tileN * 256 + col;
        int r0 = (tid >> 8) * 64;
        int cur = nid_l[r0];
        float run = bf2f(cbuf[r0 * 256 + col]);
        for (int r = r0 + 1; r < r0 + 64; ++r) {
            int nd = nid_l[r];
            float v = bf2f(cbuf[r * 256 + col]);
            if (nd != cur) {
                atomicMax((unsigned int*)&agg[(size_t)cur * DD + gcol],
                          __float_as_uint(run));
                cur = nd;
                run = v;
            } else {
                run = fmaxf(run, v);
            }
        }
        atomicMax((unsigned int*)&agg[(size_t)cur * DD + gcol], __float_as_uint(run));
    }
}

// ---------------- gather selected rows with residual add: xs[i] = x[r] + agg[r]
__global__ __launch_bounds__(128) void gather_fused(const float* __restrict__ x,
                                                    const float* __restrict__ agg,
                                                    const int* __restrict__ sel,
                                                    float* __restrict__ xs) {
    int i = blockIdx.x;
    int b = i >> 7;
    int r = b * NPG + sel[i];
    const f32x4* srcp = (const f32x4*)(x + (size_t)r * DD);
    const f32x4* aggp = (const f32x4*)(agg + (size_t)r * DD);
    f32x4 v = srcp[threadIdx.x];
    f32x4 a = aggp[threadIdx.x];
    #pragma unroll
    for (int j = 0; j < 4; ++j) v[j] += a[j];
    ((f32x4*)(xs + (size_t)i * DD))[threadIdx.x] = v;
}

extern "C" void kernel_launch(void* const* d_in, const int* in_sizes, int n_in,
                              void* d_out, int out_size, void* d_ws, size_t ws_size,
                              hipStream_t stream) {
    const float* x_in = (const float*)d_in[0];
    const int* ei = (const int*)d_in[1];
    const int* sel = (const int*)d_in[2];
    const float* W1 = (const float*)d_in[4];
    const float* b1 = (const float*)d_in[5];
    const float* W2 = (const float*)d_in[6];
    const float* b2 = (const float*)d_in[7];
    const float* g1 = (const float*)d_in[8];
    const float* be1 = (const float*)d_in[9];
    const float* g2 = (const float*)d_in[10];
    const float* be2 = (const float*)d_in[11];
    const float* fW1 = (const float*)d_in[12];
    const float* fb1 = (const float*)d_in[13];
    const float* fW2 = (const float*)d_in[14];
    const float* fb2 = (const float*)d_in[15];
    float* out = (float*)d_out;

    char* w = (char*)d_ws;
    size_t off = 0;
    auto alloc = [&](size_t bytes) -> char* {
        char* p = w + off;
        off += (bytes + 255) & ~(size_t)255;
        return p;
    };
    float* xbuf = (float*)alloc((size_t)NN * DD * 4);
    float* agg  = (float*)alloc((size_t)NN * DD * 4);
    u16* h      = (u16*)alloc((size_t)NN * DD * 2);
    u16* P      = (u16*)alloc((size_t)NN * 1024 * 2);
    u16* W1T    = (u16*)alloc((size_t)LL * 1024 * DD * 2);
    u16* W2T    = (u16*)alloc((size_t)LL * DD * DD * 2);
    u16* FW1T   = (u16*)alloc((size_t)DD * DD * 2);
    u16* FW2T   = (u16*)alloc((size_t)DD * DD * 2);
    int* cnt    = (int*)alloc((size_t)NN * 4);
    int* offs   = (int*)alloc((size_t)(NN + 1) * 4);
    int* cur    = (int*)alloc((size_t)NN * 4);
    int* ssrc   = (int*)alloc((size_t)EE * 4);
    int* sdst   = (int*)alloc((size_t)EE * 4);
    float* xs   = (float*)alloc((size_t)BBATCH * SSEL * DD * 4);
    u16* hs     = (u16*)alloc((size_t)BBATCH * SSEL * DD * 2);
    u16* uu     = (u16*)alloc((size_t)BBATCH * SSEL * DD * 2);

    const int* esrc = ei;       // edge_index[0] = x_j
    const int* edst = ei + EE;  // edge_index[1] = x_i / aggregation index

    hipMemsetAsync(cnt, 0, (size_t)NN * 4, stream);
    hist_kernel<<<EE / 256, 256, 0, stream>>>(edst, cnt);
    scan_kernel<<<1, 1024, 0, stream>>>(cnt, offs, cur);
    scatter_kernel<<<EE / 256, 256, 0, stream>>>(esrc, edst, cur, ssrc, sdst);

    for (int l = 0; l < LL; ++l) {
        cvt_w1_kernel<<<(1024 * DD + 255) / 256, 256, 0, stream>>>(
            W1 + (size_t)l * 1024 * DD, W1T + (size_t)l * 1024 * DD);
        cvt_t_kernel<<<(DD * DD + 255) / 256, 256, 0, stream>>>(
            W2 + (size_t)l * DD * DD, W2T + (size_t)l * DD * DD, DD, DD);
    }
    cvt_t_kernel<<<(DD * DD + 255) / 256, 256, 0, stream>>>(fW1, FW1T, DD, DD);
    cvt_t_kernel<<<(DD * DD + 255) / 256, 256, 0, stream>>>(fW2, FW2T, DD, DD);

    for (int l = 0; l < LL; ++l) {
        // x_l = x_{l-1} + agg ; h = LN(x_l) ; agg <- 0 for this layer's atomics
        ln_fused<<<NN, 64, 0, stream>>>(l == 0 ? x_in : xbuf, agg, xbuf, g1, be1, h,
                                        l > 0 ? 1 : 0);
        // P = h @ [W1a-W1b | W1b]   [8192 x 1024] bf16
        {
            dim3 grid(NN / 128, 1024 / 128);
            gemm_async<2><<<grid, 256, 0, stream>>>(
                h, W1T + (size_t)l * 1024 * DD, nullptr, nullptr, P, DD, 1024);
        }
        // fused: edge-combine + GEMM2 + relu + segmax-atomics into agg
        {
            dim3 grid(EE / 128, 2);
            gemm_edge<<<grid, 512, 0, stream>>>(P, ssrc, sdst,
                                                W2T + (size_t)l * DD * DD,
                                                b1 + (size_t)l * DD,
                                                b2 + (size_t)l * DD, agg);
        }
    }

    gather_fused<<<BBATCH * SSEL, 128, 0, stream>>>(xbuf, agg, sel, xs);
    ln_fused<<<BBATCH * SSEL, 64, 0, stream>>>(xs, nullptr, xs, g2, be2, hs, 0);
    dim3 gridf(BBATCH * SSEL / 128, DD / 128);
    gemm_async<0><<<gridf, 256, 0, stream>>>(hs, FW1T, fb1, nullptr, uu, DD, DD);
    gemm_async<1><<<gridf, 256, 0, stream>>>(uu, FW2T, fb2, xs, out, DD, DD);
}

// Round 4
// 779.104 us; speedup vs baseline: 2.8615x; 1.0180x over previous
//
#include <hip/hip_runtime.h>
#include <stdint.h>

#define NN 8192
#define DD 512
#define EE 131072
#define BBATCH 16
#define NPG 512
#define SSEL 128
#define LL 3

typedef unsigned short u16;
typedef __bf16 bf16x8 __attribute__((ext_vector_type(8)));
typedef float f32x4 __attribute__((ext_vector_type(4)));
typedef u16 u16x8 __attribute__((ext_vector_type(8)));

__device__ __forceinline__ float bf2f(u16 u) {
    union { unsigned i; float f; } v; v.i = ((unsigned)u) << 16; return v.f;
}
__device__ __forceinline__ u16 f2bf(float f) {
    union { unsigned i; float f; } v; v.f = f;
    unsigned i = v.i;
    return (u16)((i + 0x7FFFu + ((i >> 16) & 1u)) >> 16);  // RNE
}

// async global->LDS, 16B per lane, LDS dest = wave-uniform base + lane*16
__device__ __forceinline__ void async_cp16(const u16* g, u16* l) {
    __builtin_amdgcn_global_load_lds(
        (const __attribute__((address_space(1))) unsigned int*)g,
        (__attribute__((address_space(3))) unsigned int*)l, 16, 0, 0);
}

// ---------------- LayerNorm (+ optional residual-add + agg zeroing)
__global__ __launch_bounds__(64) void ln_fused(const float* __restrict__ xin,
                                               float* __restrict__ agg_io,
                                               float* __restrict__ xout,
                                               const float* __restrict__ g,
                                               const float* __restrict__ b,
                                               u16* __restrict__ h, int doAdd) {
    int row = blockIdx.x;
    int lane = threadIdx.x;
    const f32x4* x4 = (const f32x4*)(xin + (size_t)row * DD);
    f32x4 p = x4[lane * 2], q = x4[lane * 2 + 1];
    if (doAdd) {
        const f32x4* a4 = (const f32x4*)(agg_io + (size_t)row * DD);
        f32x4 pa = a4[lane * 2], qa = a4[lane * 2 + 1];
        #pragma unroll
        for (int i = 0; i < 4; ++i) { p[i] += pa[i]; q[i] += qa[i]; }
    }
    if (agg_io) {
        f32x4 z;
        #pragma unroll
        for (int i = 0; i < 4; ++i) z[i] = 0.f;
        f32x4* a4 = (f32x4*)(agg_io + (size_t)row * DD);
        a4[lane * 2] = z;
        a4[lane * 2 + 1] = z;
    }
    f32x4* xo = (f32x4*)(xout + (size_t)row * DD);
    xo[lane * 2] = p;
    xo[lane * 2 + 1] = q;
    float v[8];
    v[0] = p[0]; v[1] = p[1]; v[2] = p[2]; v[3] = p[3];
    v[4] = q[0]; v[5] = q[1]; v[6] = q[2]; v[7] = q[3];
    float s = 0.f, sq = 0.f;
    #pragma unroll
    for (int i = 0; i < 8; ++i) { s += v[i]; sq += v[i] * v[i]; }
    #pragma unroll
    for (int o = 32; o >= 1; o >>= 1) { s += __shfl_xor(s, o); sq += __shfl_xor(sq, o); }
    float mu = s * (1.f / DD);
    float var = sq * (1.f / DD) - mu * mu;
    float rs = rsqrtf(var + 1e-5f);
    int kb = lane * 8;
    u16x8 o8;
    #pragma unroll
    for (int i = 0; i < 8; ++i) o8[i] = f2bf((v[i] - mu) * rs * g[kb + i] + b[kb + i]);
    *(u16x8*)(h + (size_t)row * DD + kb) = o8;
}

// ---------------- counting sort by dst
__global__ void hist_kernel(const int* __restrict__ dst, int* __restrict__ cnt) {
    int e = blockIdx.x * 256 + threadIdx.x;
    if (e < EE) atomicAdd(&cnt[dst[e]], 1);
}

__global__ __launch_bounds__(1024) void scan_kernel(const int* __restrict__ cnt,
                                                    int* __restrict__ off,
                                                    int* __restrict__ cur) {
    __shared__ int part[1024];
    int t = threadIdx.x;
    int base = t * 8;
    int loc[8]; int s = 0;
    #pragma unroll
    for (int i = 0; i < 8; ++i) { loc[i] = s; s += cnt[base + i]; }
    part[t] = s;
    __syncthreads();
    for (int o = 1; o < 1024; o <<= 1) {
        int v = part[t];
        int u = (t >= o) ? part[t - o] : 0;
        __syncthreads();
        part[t] = v + u;
        __syncthreads();
    }
    int bx = (t > 0) ? part[t - 1] : 0;
    #pragma unroll
    for (int i = 0; i < 8; ++i) { off[base + i] = bx + loc[i]; cur[base + i] = bx + loc[i]; }
    if (t == 0) off[NN] = part[1023];
}

__global__ void scatter_kernel(const int* __restrict__ src, const int* __restrict__ dst,
                               int* __restrict__ cur, int* __restrict__ ssrc,
                               int* __restrict__ sdst) {
    int e = blockIdx.x * 256 + threadIdx.x;
    if (e < EE) {
        int d = dst[e];
        int p = atomicAdd(&cur[d], 1);
        ssrc[p] = src[e];
        sdst[p] = d;
    }
}

// ---------------- tiled cvt+transpose: dst[n*K+k] = bf16(src[k*Nn+n]), 32x32 tiles
__global__ __launch_bounds__(256) void cvt_t_kernel(const float* __restrict__ src,
                                                    u16* __restrict__ dstp, int K,
                                                    int Nn) {
    __shared__ u16 tile[32][33];
    int bk = blockIdx.x * 32, bn = blockIdx.y * 32;
    int tx = threadIdx.x & 31, ty = threadIdx.x >> 5;  // 32 x 8
    #pragma unroll
    for (int r = 0; r < 32; r += 8)
        tile[ty + r][tx] = f2bf(src[(size_t)(bk + ty + r) * Nn + bn + tx]);
    __syncthreads();
    #pragma unroll
    for (int r = 0; r < 32; r += 8)
        dstp[(size_t)(bn + ty + r) * K + bk + tx] = tile[tx][ty + r];
}

// W1 fp32 [1024][512] -> Wcat^T bf16 [1024 rows][512]:
// rows 0..511 = (W1a - W1b)^T ; rows 512..1023 = W1b^T. K=512, Nn=1024.
__global__ __launch_bounds__(256) void cvt_w1_kernel(const float* __restrict__ W1,
                                                     u16* __restrict__ dstp) {
    __shared__ u16 tile[32][33];
    int bk = blockIdx.x * 32, bn = blockIdx.y * 32;
    int tx = threadIdx.x & 31, ty = threadIdx.x >> 5;
    #pragma unroll
    for (int r = 0; r < 32; r += 8) {
        int k = bk + ty + r, n = bn + tx;
        float v = (n < 512) ? (W1[(size_t)k * 512 + n] - W1[(size_t)(k + 512) * 512 + n])
                            : W1[(size_t)(k + 512) * 512 + (n - 512)];
        tile[ty + r][tx] = f2bf(v);
    }
    __syncthreads();
    #pragma unroll
    for (int r = 0; r < 32; r += 8)
        dstp[(size_t)(bn + ty + r) * 512 + bk + tx] = tile[tx][ty + r];
}

// ---------------- async MFMA GEMM, 128x128 tile, 256 threads (2x2 waves)
// EMODE 0: relu(acc+bias)->bf16 ; 1: acc+bias+resid->fp32 ; 2: acc->bf16 ;
// EMODE 3: acc + (col<512 ? bias[col] : 0) -> bf16   (P-GEMM, folds b1 into Pa)
template <int EMODE>
__global__ __launch_bounds__(256) void gemm_async(
    const u16* __restrict__ A, const u16* __restrict__ BT,
    const float* __restrict__ bias, const float* __restrict__ resid,
    void* __restrict__ Cout, int K, int ldc) {
    __shared__ u16 lA[128 * 64];
    __shared__ u16 lB[128 * 64];
    const int tid = threadIdx.x;
    const int lane = tid & 63, wave = tid >> 6;
    const int wm = wave & 1, wn = wave >> 1;
    const int quad = lane >> 4, lm = lane & 15;
    const int tileM = blockIdx.x, tileN = blockIdx.y;

    const int g = (lane & 7) ^ (lane >> 3);
    const u16* ap[4];
    const u16* bp[4];
    u16* lad[4];
    u16* lbd[4];
    #pragma unroll
    for (int j = 0; j < 4; ++j) {
        int seg = wave * 4 + j;
        int rA = tileM * 128 + seg * 8 + (lane >> 3);
        int rB = tileN * 128 + seg * 8 + (lane >> 3);
        ap[j] = A + (size_t)rA * K + g * 8;
        bp[j] = BT + (size_t)rB * K + g * 8;
        lad[j] = lA + seg * 512;
        lbd[j] = lB + seg * 512;
    }

    f32x4 acc[4][4];
    #pragma unroll
    for (int mt = 0; mt < 4; ++mt)
        #pragma unroll
        for (int nt = 0; nt < 4; ++nt)
            #pragma unroll
            for (int j = 0; j < 4; ++j) acc[mt][nt][j] = 0.f;

    for (int kb = 0; kb < K; kb += 64) {
        #pragma unroll
        for (int j = 0; j < 4; ++j) {
            async_cp16(ap[j], lad[j]);
            async_cp16(bp[j], lbd[j]);
            ap[j] += 64;
            bp[j] += 64;
        }
        __syncthreads();
        #pragma unroll
        for (int kk = 0; kk < 64; kk += 32) {
            bf16x8 af[4], bfr[4];
            int gbase = (kk >> 3) + quad;
            #pragma unroll
            for (int mt = 0; mt < 4; ++mt) {
                int row = wm * 64 + mt * 16 + lm;
                af[mt] = *(const bf16x8*)(lA + row * 64 + ((gbase ^ (row & 7)) << 3));
            }
            #pragma unroll
            for (int nt = 0; nt < 4; ++nt) {
                int row = wn * 64 + nt * 16 + lm;
                bfr[nt] = *(const bf16x8*)(lB + row * 64 + ((gbase ^ (row & 7)) << 3));
            }
            #pragma unroll
            for (int mt = 0; mt < 4; ++mt)
                #pragma unroll
                for (int nt = 0; nt < 4; ++nt)
                    acc[mt][nt] = __builtin_amdgcn_mfma_f32_16x16x32_bf16(
                        af[mt], bfr[nt], acc[mt][nt], 0, 0, 0);
        }
        __syncthreads();
    }
    #pragma unroll
    for (int mt = 0; mt < 4; ++mt) {
        #pragma unroll
        for (int nt = 0; nt < 4; ++nt) {
            int col = tileN * 128 + wn * 64 + nt * 16 + lm;
            float bv;
            if (EMODE == 2) bv = 0.f;
            else if (EMODE == 3) bv = (col < 512) ? bias[col] : 0.f;
            else bv = bias[col];
            #pragma unroll
            for (int j = 0; j < 4; ++j) {
                int grow = tileM * 128 + wm * 64 + mt * 16 + quad * 4 + j;
                float v = acc[mt][nt][j] + bv;
                if (EMODE == 0) {
                    ((u16*)Cout)[(size_t)grow * ldc + col] = f2bf(fmaxf(v, 0.f));
                } else if (EMODE == 1) {
                    ((float*)Cout)[(size_t)grow * ldc + col] =
                        v + resid[(size_t)grow * ldc + col];
                } else {
                    ((u16*)Cout)[(size_t)grow * ldc + col] = f2bf(v);
                }
            }
        }
    }
}

// ---------------- fused edge GEMM, tile 128 edges x 512 cols, 512 thr (2x4 waves)
// A row e = relu(Pa'[dst]+Pb[src]) built in registers (Pa' has b1 folded in),
// prefetched one K-block ahead; B = W2T via global_load_lds; barriers keep the
// A-prefetch in flight (vmcnt(4), never 0 except last iter).
// Epilogue: relu(acc+b2) -> LDS cbuf (2 col-halves) -> run-max -> atomicMax(agg).
__global__ __launch_bounds__(512, 2) void gemm_edge(
    const u16* __restrict__ P, const int* __restrict__ ssrc,
    const int* __restrict__ sdst, const u16* __restrict__ W2T,
    const float* __restrict__ b2, float* __restrict__ agg) {
    __shared__ u16 smem[128 * 64 + 512 * 64];  // lA 16KB + lB 64KB
    __shared__ int nid_l[128];
    u16* lA = smem;
    u16* lB = smem + 128 * 64;
    const int tid = threadIdx.x;
    const int lane = tid & 63, wave = tid >> 6;  // 8 waves
    const int wm = wave & 1, wn = wave >> 1;     // wave tile 64(M) x 128(N)
    const int quad = lane >> 4, lm = lane & 15;
    const int ebase = blockIdx.x * 128;

    if (tid < 128) nid_l[tid] = sdst[ebase + tid];

    const int g = (lane & 7) ^ (lane >> 3);
    const u16* pap[2];
    const u16* pbp[2];
    u16* lout[2];
    #pragma unroll
    for (int j = 0; j < 2; ++j) {
        int seg = wave * 2 + j;
        int row = seg * 8 + (lane >> 3);
        int dn = sdst[ebase + row];
        int sn = ssrc[ebase + row];
        pap[j] = P + (size_t)dn * 1024 + g * 8;
        pbp[j] = P + (size_t)sn * 1024 + 512 + g * 8;
        lout[j] = lA + seg * 512 + lane * 8;
    }
    const u16* bp[8];
    u16* lbd[8];
    #pragma unroll
    for (int j = 0; j < 8; ++j) {
        int seg = wave * 8 + j;  // 0..63, 8 rows each
        int row = seg * 8 + (lane >> 3);
        bp[j] = W2T + (size_t)row * 512 + g * 8;
        lbd[j] = lB + seg * 512;
    }

    f32x4 acc[4][8];
    #pragma unroll
    for (int mt = 0; mt < 4; ++mt)
        #pragma unroll
        for (int nt = 0; nt < 8; ++nt)
            #pragma unroll
            for (int j = 0; j < 4; ++j) acc[mt][nt][j] = 0.f;

    // preload A-gathers for kb=0
    u16x8 apre[2][2];
    #pragma unroll
    for (int j = 0; j < 2; ++j) {
        apre[j][0] = *(const u16x8*)pap[j];
        apre[j][1] = *(const u16x8*)pbp[j];
        pap[j] += 64;
        pbp[j] += 64;
    }

    #pragma unroll 2
    for (int kb = 0; kb < 512; kb += 64) {
        // B async-copies first (drained at the barrier)...
        #pragma unroll
        for (int j = 0; j < 8; ++j) { async_cp16(bp[j], lbd[j]); bp[j] += 64; }
        asm volatile("" ::: "memory");  // ...A prefetch loads stay after them
        u16x8 anxt[2][2];
        if (kb < 448) {
            #pragma unroll
            for (int j = 0; j < 2; ++j) {
                anxt[j][0] = *(const u16x8*)pap[j];
                anxt[j][1] = *(const u16x8*)pbp[j];
                pap[j] += 64;
                pbp[j] += 64;
            }
        }
        // combine current A: t = relu(Pa' + Pb), pack round-half-up
        #pragma unroll
        for (int j = 0; j < 2; ++j) {
            union { u16x8 v; unsigned w[4]; } ua, ub;
            ua.v = apre[j][0];
            ub.v = apre[j][1];
            unsigned o[4];
            #pragma unroll
            for (int q = 0; q < 4; ++q) {
                float a0 = __uint_as_float(ua.w[q] << 16);
                float a1 = __uint_as_float(ua.w[q] & 0xffff0000u);
                float c0 = __uint_as_float(ub.w[q] << 16);
                float c1 = __uint_as_float(ub.w[q] & 0xffff0000u);
                float s0 = fmaxf(a0 + c0, 0.f);
                float s1 = fmaxf(a1 + c1, 0.f);
                unsigned r0 = __float_as_uint(s0) + 0x8000u;
                unsigned r1 = __float_as_uint(s1) + 0x8000u;
                o[q] = (r0 >> 16) | (r1 & 0xffff0000u);
            }
            *(uint4*)lout[j] = make_uint4(o[0], o[1], o[2], o[3]);
        }
        if (kb < 448)
            asm volatile("s_waitcnt lgkmcnt(0) vmcnt(4)\ns_barrier" ::: "memory");
        else
            asm volatile("s_waitcnt lgkmcnt(0) vmcnt(0)\ns_barrier" ::: "memory");
        #pragma unroll
        for (int kk = 0; kk < 64; kk += 32) {
            bf16x8 af[4], bfr[8];
            int gbase = (kk >> 3) + quad;
            #pragma unroll
            for (int mt = 0; mt < 4; ++mt) {
                int row = wm * 64 + mt * 16 + lm;
                af[mt] = *(const bf16x8*)(lA + row * 64 + ((gbase ^ (row & 7)) << 3));
            }
            #pragma unroll
            for (int nt = 0; nt < 8; ++nt) {
                int row = wn * 128 + nt * 16 + lm;
                bfr[nt] = *(const bf16x8*)(lB + row * 64 + ((gbase ^ (row & 7)) << 3));
            }
            #pragma unroll
            for (int mt = 0; mt < 4; ++mt)
                #pragma unroll
                for (int nt = 0; nt < 8; ++nt)
                    acc[mt][nt] = __builtin_amdgcn_mfma_f32_16x16x32_bf16(
                        af[mt], bfr[nt], acc[mt][nt], 0, 0, 0);
        }
        asm volatile("s_barrier" ::: "memory");
        #pragma unroll
        for (int j = 0; j < 2; ++j) {
            apre[j][0] = anxt[j][0];
            apre[j][1] = anxt[j][1];
        }
    }

    // epilogue: two col-halves through cbuf (stride 264 kills bank conflicts)
    u16* cbuf = smem;  // 128 x 264 u16 = 67584 B, aliases lA/lB
    for (int h = 0; h < 2; ++h) {
        #pragma unroll
        for (int nt = 0; nt < 4; ++nt) {
            int ntg = h * 4 + nt;
            int lcol = wn * 64 + nt * 16 + lm;
            int gcol = wn * 128 + ntg * 16 + lm;
            float bv = b2[gcol];
            #pragma unroll
            for (int mt = 0; mt < 4; ++mt) {
                #pragma unroll
                for (int j2 = 0; j2 < 4; ++j2) {
                    int row = wm * 64 + mt * 16 + quad * 4 + j2;
                    cbuf[row * 264 + lcol] = f2bf(fmaxf(acc[mt][ntg][j2] + bv, 0.f));
                }
            }
        }
        __syncthreads();
        {
            int lcol = tid & 255;
            int gcol = (lcol >> 6) * 128 + h * 64 + (lcol & 63);
            int r0 = (tid >> 8) * 64;
            int cur = nid_l[r0];
            float run = bf2f(cbuf[r0 * 264 + lcol]);
            for (int r = r0 + 1; r < r0 + 64; ++r) {
                int nd = nid_l[r];
                float v = bf2f(cbuf[r * 264 + lcol]);
                if (nd != cur) {
                    atomicMax((unsigned int*)&agg[(size_t)cur * DD + gcol],
                              __float_as_uint(run));
                    cur = nd;
                    run = v;
                } else {
                    run = fmaxf(run, v);
                }
            }
            atomicMax((unsigned int*)&agg[(size_t)cur * DD + gcol],
                      __float_as_uint(run));
        }
        __syncthreads();
    }
}

// ---------------- gather selected rows with residual add: xs[i] = x[r] + agg[r]
__global__ __launch_bounds__(128) void gather_fused(const float* __restrict__ x,
                                                    const float* __restrict__ agg,
                                                    const int* __restrict__ sel,
                                                    float* __restrict__ xs) {
    int i = blockIdx.x;
    int b = i >> 7;
    int r = b * NPG + sel[i];
    const f32x4* srcp = (const f32x4*)(x + (size_t)r * DD);
    const f32x4* aggp = (const f32x4*)(agg + (size_t)r * DD);
    f32x4 v = srcp[threadIdx.x];
    f32x4 a = aggp[threadIdx.x];
    #pragma unroll
    for (int j = 0; j < 4; ++j) v[j] += a[j];
    ((f32x4*)(xs + (size_t)i * DD))[threadIdx.x] = v;
}

extern "C" void kernel_launch(void* const* d_in, const int* in_sizes, int n_in,
                              void* d_out, int out_size, void* d_ws, size_t ws_size,
                              hipStream_t stream) {
    const float* x_in = (const float*)d_in[0];
    const int* ei = (const int*)d_in[1];
    const int* sel = (const int*)d_in[2];
    const float* W1 = (const float*)d_in[4];
    const float* b1 = (const float*)d_in[5];
    const float* W2 = (const float*)d_in[6];
    const float* b2 = (const float*)d_in[7];
    const float* g1 = (const float*)d_in[8];
    const float* be1 = (const float*)d_in[9];
    const float* g2 = (const float*)d_in[10];
    const float* be2 = (const float*)d_in[11];
    const float* fW1 = (const float*)d_in[12];
    const float* fb1 = (const float*)d_in[13];
    const float* fW2 = (const float*)d_in[14];
    const float* fb2 = (const float*)d_in[15];
    float* out = (float*)d_out;

    char* w = (char*)d_ws;
    size_t off = 0;
    auto alloc = [&](size_t bytes) -> char* {
        char* p = w + off;
        off += (bytes + 255) & ~(size_t)255;
        return p;
    };
    float* xbuf = (float*)alloc((size_t)NN * DD * 4);
    float* agg  = (float*)alloc((size_t)NN * DD * 4);
    u16* h      = (u16*)alloc((size_t)NN * DD * 2);
    u16* P      = (u16*)alloc((size_t)NN * 1024 * 2);
    u16* W1T    = (u16*)alloc((size_t)LL * 1024 * DD * 2);
    u16* W2T    = (u16*)alloc((size_t)LL * DD * DD * 2);
    u16* FW1T   = (u16*)alloc((size_t)DD * DD * 2);
    u16* FW2T   = (u16*)alloc((size_t)DD * DD * 2);
    int* cnt    = (int*)alloc((size_t)NN * 4);
    int* offs   = (int*)alloc((size_t)(NN + 1) * 4);
    int* cur    = (int*)alloc((size_t)NN * 4);
    int* ssrc   = (int*)alloc((size_t)EE * 4);
    int* sdst   = (int*)alloc((size_t)EE * 4);
    float* xs   = (float*)alloc((size_t)BBATCH * SSEL * DD * 4);
    u16* hs     = (u16*)alloc((size_t)BBATCH * SSEL * DD * 2);
    u16* uu     = (u16*)alloc((size_t)BBATCH * SSEL * DD * 2);

    const int* esrc = ei;       // edge_index[0] = x_j
    const int* edst = ei + EE;  // edge_index[1] = x_i / aggregation index

    hipMemsetAsync(cnt, 0, (size_t)NN * 4, stream);
    hist_kernel<<<EE / 256, 256, 0, stream>>>(edst, cnt);
    scan_kernel<<<1, 1024, 0, stream>>>(cnt, offs, cur);
    scatter_kernel<<<EE / 256, 256, 0, stream>>>(esrc, edst, cur, ssrc, sdst);

    for (int l = 0; l < LL; ++l) {
        cvt_w1_kernel<<<dim3(16, 32), 256, 0, stream>>>(
            W1 + (size_t)l * 1024 * DD, W1T + (size_t)l * 1024 * DD);
        cvt_t_kernel<<<dim3(16, 16), 256, 0, stream>>>(
            W2 + (size_t)l * DD * DD, W2T + (size_t)l * DD * DD, DD, DD);
    }
    cvt_t_kernel<<<dim3(16, 16), 256, 0, stream>>>(fW1, FW1T, DD, DD);
    cvt_t_kernel<<<dim3(16, 16), 256, 0, stream>>>(fW2, FW2T, DD, DD);

    for (int l = 0; l < LL; ++l) {
        // x_l = x_{l-1} + agg ; h = LN(x_l) ; agg <- 0 for this layer's atomics
        ln_fused<<<NN, 64, 0, stream>>>(l == 0 ? x_in : xbuf, agg, xbuf, g1, be1, h,
                                        l > 0 ? 1 : 0);
        // P = h @ [W1a-W1b | W1b] + [b1 | 0]   [8192 x 1024] bf16
        {
            dim3 grid(NN / 128, 1024 / 128);
            gemm_async<3><<<grid, 256, 0, stream>>>(
                h, W1T + (size_t)l * 1024 * DD, b1 + (size_t)l * DD, nullptr, P, DD,
                1024);
        }
        // fused: edge-combine + GEMM2 + relu + segmax-atomics into agg
        gemm_edge<<<EE / 128, 512, 0, stream>>>(P, ssrc, sdst,
                                                W2T + (size_t)l * DD * DD,
                                                b2 + (size_t)l * DD, agg);
    }

    gather_fused<<<BBATCH * SSEL, 128, 0, stream>>>(xbuf, agg, sel, xs);
    ln_fused<<<BBATCH * SSEL, 64, 0, stream>>>(xs, nullptr, xs, g2, be2, hs, 0);
    dim3 gridf(BBATCH * SSEL / 128, DD / 128);
    gemm_async<0><<<gridf, 256, 0, stream>>>(hs, FW1T, fb1, nullptr, uu, DD, DD);
    gemm_async<1><<<gridf, 256, 0, stream>>>(uu, FW2T, fb2, xs, out, DD, DD);
}

// Round 5
// 694.685 us; speedup vs baseline: 3.2092x; 1.1215x over previous
//
#include <hip/hip_runtime.h>
#include <stdint.h>

#define NN 8192
#define DD 512
#define EE 131072
#define BBATCH 16
#define NPG 512
#define SSEL 128
#define LL 3

typedef unsigned short u16;
typedef __bf16 bf16x8 __attribute__((ext_vector_type(8)));
typedef float f32x4 __attribute__((ext_vector_type(4)));
typedef u16 u16x8 __attribute__((ext_vector_type(8)));

__device__ __forceinline__ float bf2f(u16 u) {
    union { unsigned i; float f; } v; v.i = ((unsigned)u) << 16; return v.f;
}
__device__ __forceinline__ u16 f2bf(float f) {
    union { unsigned i; float f; } v; v.f = f;
    unsigned i = v.i;
    return (u16)((i + 0x7FFFu + ((i >> 16) & 1u)) >> 16);  // RNE
}

// async global->LDS, 16B per lane, LDS dest = wave-uniform base + lane*16
__device__ __forceinline__ void async_cp16(const u16* g, u16* l) {
    __builtin_amdgcn_global_load_lds(
        (const __attribute__((address_space(1))) unsigned int*)g,
        (__attribute__((address_space(3))) unsigned int*)l, 16, 0, 0);
}

// ---------------- LayerNorm (+ optional residual-add + agg zeroing)
__global__ __launch_bounds__(64) void ln_fused(const float* __restrict__ xin,
                                               float* __restrict__ agg_io,
                                               float* __restrict__ xout,
                                               const float* __restrict__ g,
                                               const float* __restrict__ b,
                                               u16* __restrict__ h, int doAdd) {
    int row = blockIdx.x;
    int lane = threadIdx.x;
    const f32x4* x4 = (const f32x4*)(xin + (size_t)row * DD);
    f32x4 p = x4[lane * 2], q = x4[lane * 2 + 1];
    if (doAdd) {
        const f32x4* a4 = (const f32x4*)(agg_io + (size_t)row * DD);
        f32x4 pa = a4[lane * 2], qa = a4[lane * 2 + 1];
        #pragma unroll
        for (int i = 0; i < 4; ++i) { p[i] += pa[i]; q[i] += qa[i]; }
    }
    if (agg_io) {
        f32x4 z;
        #pragma unroll
        for (int i = 0; i < 4; ++i) z[i] = 0.f;
        f32x4* a4 = (f32x4*)(agg_io + (size_t)row * DD);
        a4[lane * 2] = z;
        a4[lane * 2 + 1] = z;
    }
    f32x4* xo = (f32x4*)(xout + (size_t)row * DD);
    xo[lane * 2] = p;
    xo[lane * 2 + 1] = q;
    float v[8];
    v[0] = p[0]; v[1] = p[1]; v[2] = p[2]; v[3] = p[3];
    v[4] = q[0]; v[5] = q[1]; v[6] = q[2]; v[7] = q[3];
    float s = 0.f, sq = 0.f;
    #pragma unroll
    for (int i = 0; i < 8; ++i) { s += v[i]; sq += v[i] * v[i]; }
    #pragma unroll
    for (int o = 32; o >= 1; o >>= 1) { s += __shfl_xor(s, o); sq += __shfl_xor(sq, o); }
    float mu = s * (1.f / DD);
    float var = sq * (1.f / DD) - mu * mu;
    float rs = rsqrtf(var + 1e-5f);
    int kb = lane * 8;
    u16x8 o8;
    #pragma unroll
    for (int i = 0; i < 8; ++i) o8[i] = f2bf((v[i] - mu) * rs * g[kb + i] + b[kb + i]);
    *(u16x8*)(h + (size_t)row * DD + kb) = o8;
}

// ---------------- counting sort by dst
__global__ void hist_kernel(const int* __restrict__ dst, int* __restrict__ cnt) {
    int e = blockIdx.x * 256 + threadIdx.x;
    if (e < EE) atomicAdd(&cnt[dst[e]], 1);
}

__global__ __launch_bounds__(1024) void scan_kernel(const int* __restrict__ cnt,
                                                    int* __restrict__ off,
                                                    int* __restrict__ cur) {
    __shared__ int part[1024];
    int t = threadIdx.x;
    int base = t * 8;
    int loc[8]; int s = 0;
    #pragma unroll
    for (int i = 0; i < 8; ++i) { loc[i] = s; s += cnt[base + i]; }
    part[t] = s;
    __syncthreads();
    for (int o = 1; o < 1024; o <<= 1) {
        int v = part[t];
        int u = (t >= o) ? part[t - o] : 0;
        __syncthreads();
        part[t] = v + u;
        __syncthreads();
    }
    int bx = (t > 0) ? part[t - 1] : 0;
    #pragma unroll
    for (int i = 0; i < 8; ++i) { off[base + i] = bx + loc[i]; cur[base + i] = bx + loc[i]; }
    if (t == 0) off[NN] = part[1023];
}

__global__ void scatter_kernel(const int* __restrict__ src, const int* __restrict__ dst,
                               int* __restrict__ cur, int* __restrict__ ssrc,
                               int* __restrict__ sdst) {
    int e = blockIdx.x * 256 + threadIdx.x;
    if (e < EE) {
        int d = dst[e];
        int p = atomicAdd(&cur[d], 1);
        ssrc[p] = src[e];
        sdst[p] = d;
    }
}

// ---------------- tiled cvt+transpose: dst[n*K+k] = bf16(src[k*Nn+n]), 32x32 tiles
__global__ __launch_bounds__(256) void cvt_t_kernel(const float* __restrict__ src,
                                                    u16* __restrict__ dstp, int K,
                                                    int Nn) {
    __shared__ u16 tile[32][33];
    int bk = blockIdx.x * 32, bn = blockIdx.y * 32;
    int tx = threadIdx.x & 31, ty = threadIdx.x >> 5;  // 32 x 8
    #pragma unroll
    for (int r = 0; r < 32; r += 8)
        tile[ty + r][tx] = f2bf(src[(size_t)(bk + ty + r) * Nn + bn + tx]);
    __syncthreads();
    #pragma unroll
    for (int r = 0; r < 32; r += 8)
        dstp[(size_t)(bn + ty + r) * K + bk + tx] = tile[tx][ty + r];
}

// W1 fp32 [1024][512] -> Wcat^T bf16 [1024 rows][512]:
// rows 0..511 = (W1a - W1b)^T ; rows 512..1023 = W1b^T. K=512, Nn=1024.
__global__ __launch_bounds__(256) void cvt_w1_kernel(const float* __restrict__ W1,
                                                     u16* __restrict__ dstp) {
    __shared__ u16 tile[32][33];
    int bk = blockIdx.x * 32, bn = blockIdx.y * 32;
    int tx = threadIdx.x & 31, ty = threadIdx.x >> 5;
    #pragma unroll
    for (int r = 0; r < 32; r += 8) {
        int k = bk + ty + r, n = bn + tx;
        float v = (n < 512) ? (W1[(size_t)k * 512 + n] - W1[(size_t)(k + 512) * 512 + n])
                            : W1[(size_t)(k + 512) * 512 + (n - 512)];
        tile[ty + r][tx] = f2bf(v);
    }
    __syncthreads();
    #pragma unroll
    for (int r = 0; r < 32; r += 8)
        dstp[(size_t)(bn + ty + r) * 512 + bk + tx] = tile[tx][ty + r];
}

// ---------------- async MFMA GEMM, 128x128 tile, 256 threads (2x2 waves)
// EMODE 0: relu(acc+bias)->bf16 ; 1: acc+bias+resid->fp32 ; 2: acc->bf16 ;
// EMODE 3: acc + (col<512 ? bias[col] : 0) -> bf16   (P-GEMM, folds b1 into Pa)
template <int EMODE>
__global__ __launch_bounds__(256) void gemm_async(
    const u16* __restrict__ A, const u16* __restrict__ BT,
    const float* __restrict__ bias, const float* __restrict__ resid,
    void* __restrict__ Cout, int K, int ldc) {
    __shared__ u16 lA[128 * 64];
    __shared__ u16 lB[128 * 64];
    const int tid = threadIdx.x;
    const int lane = tid & 63, wave = tid >> 6;
    const int wm = wave & 1, wn = wave >> 1;
    const int quad = lane >> 4, lm = lane & 15;
    const int tileM = blockIdx.x, tileN = blockIdx.y;

    const int g = (lane & 7) ^ (lane >> 3);
    const u16* ap[4];
    const u16* bp[4];
    u16* lad[4];
    u16* lbd[4];
    #pragma unroll
    for (int j = 0; j < 4; ++j) {
        int seg = wave * 4 + j;
        int rA = tileM * 128 + seg * 8 + (lane >> 3);
        int rB = tileN * 128 + seg * 8 + (lane >> 3);
        ap[j] = A + (size_t)rA * K + g * 8;
        bp[j] = BT + (size_t)rB * K + g * 8;
        lad[j] = lA + seg * 512;
        lbd[j] = lB + seg * 512;
    }

    f32x4 acc[4][4];
    #pragma unroll
    for (int mt = 0; mt < 4; ++mt)
        #pragma unroll
        for (int nt = 0; nt < 4; ++nt)
            #pragma unroll
            for (int j = 0; j < 4; ++j) acc[mt][nt][j] = 0.f;

    for (int kb = 0; kb < K; kb += 64) {
        #pragma unroll
        for (int j = 0; j < 4; ++j) {
            async_cp16(ap[j], lad[j]);
            async_cp16(bp[j], lbd[j]);
            ap[j] += 64;
            bp[j] += 64;
        }
        __syncthreads();
        #pragma unroll
        for (int kk = 0; kk < 64; kk += 32) {
            bf16x8 af[4], bfr[4];
            int gbase = (kk >> 3) + quad;
            #pragma unroll
            for (int mt = 0; mt < 4; ++mt) {
                int row = wm * 64 + mt * 16 + lm;
                af[mt] = *(const bf16x8*)(lA + row * 64 + ((gbase ^ (row & 7)) << 3));
            }
            #pragma unroll
            for (int nt = 0; nt < 4; ++nt) {
                int row = wn * 64 + nt * 16 + lm;
                bfr[nt] = *(const bf16x8*)(lB + row * 64 + ((gbase ^ (row & 7)) << 3));
            }
            #pragma unroll
            for (int mt = 0; mt < 4; ++mt)
                #pragma unroll
                for (int nt = 0; nt < 4; ++nt)
                    acc[mt][nt] = __builtin_amdgcn_mfma_f32_16x16x32_bf16(
                        af[mt], bfr[nt], acc[mt][nt], 0, 0, 0);
        }
        __syncthreads();
    }
    #pragma unroll
    for (int mt = 0; mt < 4; ++mt) {
        #pragma unroll
        for (int nt = 0; nt < 4; ++nt) {
            int col = tileN * 128 + wn * 64 + nt * 16 + lm;
            float bv;
            if (EMODE == 2) bv = 0.f;
            else if (EMODE == 3) bv = (col < 512) ? bias[col] : 0.f;
            else bv = bias[col];
            #pragma unroll
            for (int j = 0; j < 4; ++j) {
                int grow = tileM * 128 + wm * 64 + mt * 16 + quad * 4 + j;
                float v = acc[mt][nt][j] + bv;
                if (EMODE == 0) {
                    ((u16*)Cout)[(size_t)grow * ldc + col] = f2bf(fmaxf(v, 0.f));
                } else if (EMODE == 1) {
                    ((float*)Cout)[(size_t)grow * ldc + col] =
                        v + resid[(size_t)grow * ldc + col];
                } else {
                    ((u16*)Cout)[(size_t)grow * ldc + col] = f2bf(v);
                }
            }
        }
    }
}

// ---------------- fused edge GEMM, tile 128 edges x 256 cols, 512 thr (8 waves,
// wave-tile 64x64). LDS lA 16KB + lB 32KB (~48.5KB total) -> 2-3 blocks/CU.
// A row e = relu(Pa'[dst]+Pb[src]) built in registers (b1 folded into Pa'),
// prefetched one K-block ahead; B = W2T via global_load_lds; vmcnt(4) barrier
// keeps the A-prefetch in flight. Epilogue: 2 passes of 64 rows through cbuf
// (stride 264) -> 32-row run-max windows -> atomicMax(agg) (split runs OK: max
// is idempotent).
__global__ __launch_bounds__(512, 2) void gemm_edge(
    const u16* __restrict__ P, const int* __restrict__ ssrc,
    const int* __restrict__ sdst, const u16* __restrict__ W2T,
    const float* __restrict__ b2, float* __restrict__ agg) {
    __shared__ u16 smem[128 * 64 + 256 * 64];  // lA 16KB + lB 32KB
    __shared__ int nid_l[128];
    u16* lA = smem;
    u16* lB = smem + 128 * 64;
    const int tid = threadIdx.x;
    const int lane = tid & 63, wave = tid >> 6;  // 8 waves
    const int wm = wave & 1, wn = wave >> 1;     // wave tile 64(M) x 64(N)
    const int quad = lane >> 4, lm = lane & 15;
    const int tileN = blockIdx.x;                // 0..1  (col half)
    const int ebase = blockIdx.y * 128;

    if (tid < 128) nid_l[tid] = sdst[ebase + tid];

    const int g = (lane & 7) ^ (lane >> 3);
    // A staging: 2 segments of 8 rows per thread-group
    const u16* pap[2];
    const u16* pbp[2];
    u16* lout[2];
    #pragma unroll
    for (int j = 0; j < 2; ++j) {
        int seg = wave * 2 + j;
        int row = seg * 8 + (lane >> 3);
        int dn = sdst[ebase + row];
        int sn = ssrc[ebase + row];
        pap[j] = P + (size_t)dn * 1024 + g * 8;
        pbp[j] = P + (size_t)sn * 1024 + 512 + g * 8;
        lout[j] = lA + seg * 512 + lane * 8;
    }
    // B async staging: 4 segments of 8 rows per wave (256 rows total)
    const u16* bp[4];
    u16* lbd[4];
    #pragma unroll
    for (int j = 0; j < 4; ++j) {
        int seg = wave * 4 + j;  // 0..31
        int row = tileN * 256 + seg * 8 + (lane >> 3);
        bp[j] = W2T + (size_t)row * 512 + g * 8;
        lbd[j] = lB + seg * 512;
    }

    f32x4 acc[4][4];
    #pragma unroll
    for (int mt = 0; mt < 4; ++mt)
        #pragma unroll
        for (int nt = 0; nt < 4; ++nt)
            #pragma unroll
            for (int j = 0; j < 4; ++j) acc[mt][nt][j] = 0.f;

    // preload A-gathers for kb=0
    u16x8 apre[2][2];
    #pragma unroll
    for (int j = 0; j < 2; ++j) {
        apre[j][0] = *(const u16x8*)pap[j];
        apre[j][1] = *(const u16x8*)pbp[j];
        pap[j] += 64;
        pbp[j] += 64;
    }

    #pragma unroll 2
    for (int kb = 0; kb < 512; kb += 64) {
        // B async-copies first (drained at the barrier)...
        #pragma unroll
        for (int j = 0; j < 4; ++j) { async_cp16(bp[j], lbd[j]); bp[j] += 64; }
        asm volatile("" ::: "memory");  // ...A prefetch loads stay after them
        u16x8 anxt[2][2];
        if (kb < 448) {
            #pragma unroll
            for (int j = 0; j < 2; ++j) {
                anxt[j][0] = *(const u16x8*)pap[j];
                anxt[j][1] = *(const u16x8*)pbp[j];
                pap[j] += 64;
                pbp[j] += 64;
            }
        }
        // combine current A: t = relu(Pa' + Pb), pack round-half-up
        #pragma unroll
        for (int j = 0; j < 2; ++j) {
            union { u16x8 v; unsigned w[4]; } ua, ub;
            ua.v = apre[j][0];
            ub.v = apre[j][1];
            unsigned o[4];
            #pragma unroll
            for (int q = 0; q < 4; ++q) {
                float a0 = __uint_as_float(ua.w[q] << 16);
                float a1 = __uint_as_float(ua.w[q] & 0xffff0000u);
                float c0 = __uint_as_float(ub.w[q] << 16);
                float c1 = __uint_as_float(ub.w[q] & 0xffff0000u);
                float s0 = fmaxf(a0 + c0, 0.f);
                float s1 = fmaxf(a1 + c1, 0.f);
                unsigned r0 = __float_as_uint(s0) + 0x8000u;
                unsigned r1 = __float_as_uint(s1) + 0x8000u;
                o[q] = (r0 >> 16) | (r1 & 0xffff0000u);
            }
            *(uint4*)lout[j] = make_uint4(o[0], o[1], o[2], o[3]);
        }
        if (kb < 448)
            asm volatile("s_waitcnt lgkmcnt(0) vmcnt(4)\ns_barrier" ::: "memory");
        else
            asm volatile("s_waitcnt lgkmcnt(0) vmcnt(0)\ns_barrier" ::: "memory");
        #pragma unroll
        for (int kk = 0; kk < 64; kk += 32) {
            bf16x8 af[4], bfr[4];
            int gbase = (kk >> 3) + quad;
            #pragma unroll
            for (int mt = 0; mt < 4; ++mt) {
                int row = wm * 64 + mt * 16 + lm;
                af[mt] = *(const bf16x8*)(lA + row * 64 + ((gbase ^ (row & 7)) << 3));
            }
            #pragma unroll
            for (int nt = 0; nt < 4; ++nt) {
                int row = wn * 64 + nt * 16 + lm;
                bfr[nt] = *(const bf16x8*)(lB + row * 64 + ((gbase ^ (row & 7)) << 3));
            }
            #pragma unroll
            for (int mt = 0; mt < 4; ++mt)
                #pragma unroll
                for (int nt = 0; nt < 4; ++nt)
                    acc[mt][nt] = __builtin_amdgcn_mfma_f32_16x16x32_bf16(
                        af[mt], bfr[nt], acc[mt][nt], 0, 0, 0);
        }
        asm volatile("s_barrier" ::: "memory");
        #pragma unroll
        for (int j = 0; j < 2; ++j) {
            apre[j][0] = anxt[j][0];
            apre[j][1] = anxt[j][1];
        }
    }

    // epilogue: 2 passes of 64 rows; cbuf 64 x 264 (33.8KB, aliases lA/lB)
    u16* cbuf = smem;
    for (int p = 0; p < 2; ++p) {
        if (wm == p) {
            #pragma unroll
            for (int nt = 0; nt < 4; ++nt) {
                int lcol = wn * 64 + nt * 16 + lm;
                float bv = b2[tileN * 256 + lcol];
                #pragma unroll
                for (int mt = 0; mt < 4; ++mt) {
                    #pragma unroll
                    for (int j2 = 0; j2 < 4; ++j2) {
                        int row = mt * 16 + quad * 4 + j2;  // 0..63 within pass
                        cbuf[row * 264 + lcol] = f2bf(fmaxf(acc[mt][nt][j2] + bv, 0.f));
                    }
                }
            }
        }
        __syncthreads();
        {
            int lcol = tid & 255;
            int gcol = tileN * 256 + lcol;
            int r0 = (tid >> 8) * 32;  // 0 or 32 within the 64-row pass
            int gr0 = p * 64 + r0;     // row within the 128-edge tile
            int cur = nid_l[gr0];
            float run = bf2f(cbuf[r0 * 264 + lcol]);
            for (int r = 1; r < 32; ++r) {
                int nd = nid_l[gr0 + r];
                float v = bf2f(cbuf[(r0 + r) * 264 + lcol]);
                if (nd != cur) {
                    atomicMax((unsigned int*)&agg[(size_t)cur * DD + gcol],
                              __float_as_uint(run));
                    cur = nd;
                    run = v;
                } else {
                    run = fmaxf(run, v);
                }
            }
            atomicMax((unsigned int*)&agg[(size_t)cur * DD + gcol],
                      __float_as_uint(run));
        }
        __syncthreads();
    }
}

// ---------------- gather selected rows with residual add: xs[i] = x[r] + agg[r]
__global__ __launch_bounds__(128) void gather_fused(const float* __restrict__ x,
                                                    const float* __restrict__ agg,
                                                    const int* __restrict__ sel,
                                                    float* __restrict__ xs) {
    int i = blockIdx.x;
    int b = i >> 7;
    int r = b * NPG + sel[i];
    const f32x4* srcp = (const f32x4*)(x + (size_t)r * DD);
    const f32x4* aggp = (const f32x4*)(agg + (size_t)r * DD);
    f32x4 v = srcp[threadIdx.x];
    f32x4 a = aggp[threadIdx.x];
    #pragma unroll
    for (int j = 0; j < 4; ++j) v[j] += a[j];
    ((f32x4*)(xs + (size_t)i * DD))[threadIdx.x] = v;
}

extern "C" void kernel_launch(void* const* d_in, const int* in_sizes, int n_in,
                              void* d_out, int out_size, void* d_ws, size_t ws_size,
                              hipStream_t stream) {
    const float* x_in = (const float*)d_in[0];
    const int* ei = (const int*)d_in[1];
    const int* sel = (const int*)d_in[2];
    const float* W1 = (const float*)d_in[4];
    const float* b1 = (const float*)d_in[5];
    const float* W2 = (const float*)d_in[6];
    const float* b2 = (const float*)d_in[7];
    const float* g1 = (const float*)d_in[8];
    const float* be1 = (const float*)d_in[9];
    const float* g2 = (const float*)d_in[10];
    const float* be2 = (const float*)d_in[11];
    const float* fW1 = (const float*)d_in[12];
    const float* fb1 = (const float*)d_in[13];
    const float* fW2 = (const float*)d_in[14];
    const float* fb2 = (const float*)d_in[15];
    float* out = (float*)d_out;

    char* w = (char*)d_ws;
    size_t off = 0;
    auto alloc = [&](size_t bytes) -> char* {
        char* p = w + off;
        off += (bytes + 255) & ~(size_t)255;
        return p;
    };
    float* xbuf = (float*)alloc((size_t)NN * DD * 4);
    float* agg  = (float*)alloc((size_t)NN * DD * 4);
    u16* h      = (u16*)alloc((size_t)NN * DD * 2);
    u16* P      = (u16*)alloc((size_t)NN * 1024 * 2);
    u16* W1T    = (u16*)alloc((size_t)LL * 1024 * DD * 2);
    u16* W2T    = (u16*)alloc((size_t)LL * DD * DD * 2);
    u16* FW1T   = (u16*)alloc((size_t)DD * DD * 2);
    u16* FW2T   = (u16*)alloc((size_t)DD * DD * 2);
    int* cnt    = (int*)alloc((size_t)NN * 4);
    int* offs   = (int*)alloc((size_t)(NN + 1) * 4);
    int* cur    = (int*)alloc((size_t)NN * 4);
    int* ssrc   = (int*)alloc((size_t)EE * 4);
    int* sdst   = (int*)alloc((size_t)EE * 4);
    float* xs   = (float*)alloc((size_t)BBATCH * SSEL * DD * 4);
    u16* hs     = (u16*)alloc((size_t)BBATCH * SSEL * DD * 2);
    u16* uu     = (u16*)alloc((size_t)BBATCH * SSEL * DD * 2);

    const int* esrc = ei;       // edge_index[0] = x_j
    const int* edst = ei + EE;  // edge_index[1] = x_i / aggregation index

    hipMemsetAsync(cnt, 0, (size_t)NN * 4, stream);
    hist_kernel<<<EE / 256, 256, 0, stream>>>(edst, cnt);
    scan_kernel<<<1, 1024, 0, stream>>>(cnt, offs, cur);
    scatter_kernel<<<EE / 256, 256, 0, stream>>>(esrc, edst, cur, ssrc, sdst);

    for (int l = 0; l < LL; ++l) {
        cvt_w1_kernel<<<dim3(16, 32), 256, 0, stream>>>(
            W1 + (size_t)l * 1024 * DD, W1T + (size_t)l * 1024 * DD);
        cvt_t_kernel<<<dim3(16, 16), 256, 0, stream>>>(
            W2 + (size_t)l * DD * DD, W2T + (size_t)l * DD * DD, DD, DD);
    }
    cvt_t_kernel<<<dim3(16, 16), 256, 0, stream>>>(fW1, FW1T, DD, DD);
    cvt_t_kernel<<<dim3(16, 16), 256, 0, stream>>>(fW2, FW2T, DD, DD);

    for (int l = 0; l < LL; ++l) {
        // x_l = x_{l-1} + agg ; h = LN(x_l) ; agg <- 0 for this layer's atomics
        ln_fused<<<NN, 64, 0, stream>>>(l == 0 ? x_in : xbuf, agg, xbuf, g1, be1, h,
                                        l > 0 ? 1 : 0);
        // P = h @ [W1a-W1b | W1b] + [b1 | 0]   [8192 x 1024] bf16
        {
            dim3 grid(NN / 128, 1024 / 128);
            gemm_async<3><<<grid, 256, 0, stream>>>(
                h, W1T + (size_t)l * 1024 * DD, b1 + (size_t)l * DD, nullptr, P, DD,
                1024);
        }
        // fused: edge-combine + GEMM2 + relu + segmax-atomics into agg
        gemm_edge<<<dim3(2, EE / 128), 512, 0, stream>>>(
            P, ssrc, sdst, W2T + (size_t)l * DD * DD, b2 + (size_t)l * DD, agg);
    }

    gather_fused<<<BBATCH * SSEL, 128, 0, stream>>>(xbuf, agg, sel, xs);
    ln_fused<<<BBATCH * SSEL, 64, 0, stream>>>(xs, nullptr, xs, g2, be2, hs, 0);
    dim3 gridf(BBATCH * SSEL / 128, DD / 128);
    gemm_async<0><<<gridf, 256, 0, stream>>>(hs, FW1T, fb1, nullptr, uu, DD, DD);
    gemm_async<1><<<gridf, 256, 0, stream>>>(uu, FW2T, fb2, xs, out, DD, DD);
}

// Round 6
// 620.175 us; speedup vs baseline: 3.5948x; 1.1201x over previous
//
#include <hip/hip_runtime.h>
#include <stdint.h>

#define NN 8192
#define DD 512
#define EE 131072
#define BBATCH 16
#define NPG 512
#define SSEL 128
#define LL 3

typedef unsigned short u16;
typedef __bf16 bf16x8 __attribute__((ext_vector_type(8)));
typedef float f32x4 __attribute__((ext_vector_type(4)));
typedef u16 u16x8 __attribute__((ext_vector_type(8)));

__device__ __forceinline__ float bf2f(u16 u) {
    union { unsigned i; float f; } v; v.i = ((unsigned)u) << 16; return v.f;
}
__device__ __forceinline__ u16 f2bf(float f) {
    union { unsigned i; float f; } v; v.f = f;
    unsigned i = v.i;
    return (u16)((i + 0x7FFFu + ((i >> 16) & 1u)) >> 16);  // RNE
}

// async global->LDS, 16B per lane, LDS dest = wave-uniform base + lane*16
__device__ __forceinline__ void async_cp16(const u16* g, u16* l) {
    __builtin_amdgcn_global_load_lds(
        (const __attribute__((address_space(1))) unsigned int*)g,
        (__attribute__((address_space(3))) unsigned int*)l, 16, 0, 0);
}

// ---------------- LayerNorm (+ optional residual-add + agg zeroing)
__global__ __launch_bounds__(64) void ln_fused(const float* __restrict__ xin,
                                               float* __restrict__ agg_io,
                                               float* __restrict__ xout,
                                               const float* __restrict__ g,
                                               const float* __restrict__ b,
                                               u16* __restrict__ h, int doAdd) {
    int row = blockIdx.x;
    int lane = threadIdx.x;
    const f32x4* x4 = (const f32x4*)(xin + (size_t)row * DD);
    f32x4 p = x4[lane * 2], q = x4[lane * 2 + 1];
    if (doAdd) {
        const f32x4* a4 = (const f32x4*)(agg_io + (size_t)row * DD);
        f32x4 pa = a4[lane * 2], qa = a4[lane * 2 + 1];
        #pragma unroll
        for (int i = 0; i < 4; ++i) { p[i] += pa[i]; q[i] += qa[i]; }
    }
    if (agg_io) {
        f32x4 z;
        #pragma unroll
        for (int i = 0; i < 4; ++i) z[i] = 0.f;
        f32x4* a4 = (f32x4*)(agg_io + (size_t)row * DD);
        a4[lane * 2] = z;
        a4[lane * 2 + 1] = z;
    }
    f32x4* xo = (f32x4*)(xout + (size_t)row * DD);
    xo[lane * 2] = p;
    xo[lane * 2 + 1] = q;
    float v[8];
    v[0] = p[0]; v[1] = p[1]; v[2] = p[2]; v[3] = p[3];
    v[4] = q[0]; v[5] = q[1]; v[6] = q[2]; v[7] = q[3];
    float s = 0.f, sq = 0.f;
    #pragma unroll
    for (int i = 0; i < 8; ++i) { s += v[i]; sq += v[i] * v[i]; }
    #pragma unroll
    for (int o = 32; o >= 1; o >>= 1) { s += __shfl_xor(s, o); sq += __shfl_xor(sq, o); }
    float mu = s * (1.f / DD);
    float var = sq * (1.f / DD) - mu * mu;
    float rs = rsqrtf(var + 1e-5f);
    int kb = lane * 8;
    u16x8 o8;
    #pragma unroll
    for (int i = 0; i < 8; ++i) o8[i] = f2bf((v[i] - mu) * rs * g[kb + i] + b[kb + i]);
    *(u16x8*)(h + (size_t)row * DD + kb) = o8;
}

// ---------------- counting sort by dst
__global__ void hist_kernel(const int* __restrict__ dst, int* __restrict__ cnt) {
    int e = blockIdx.x * 256 + threadIdx.x;
    if (e < EE) atomicAdd(&cnt[dst[e]], 1);
}

__global__ __launch_bounds__(1024) void scan_kernel(const int* __restrict__ cnt,
                                                    int* __restrict__ off,
                                                    int* __restrict__ cur) {
    __shared__ int part[1024];
    int t = threadIdx.x;
    int base = t * 8;
    int loc[8]; int s = 0;
    #pragma unroll
    for (int i = 0; i < 8; ++i) { loc[i] = s; s += cnt[base + i]; }
    part[t] = s;
    __syncthreads();
    for (int o = 1; o < 1024; o <<= 1) {
        int v = part[t];
        int u = (t >= o) ? part[t - o] : 0;
        __syncthreads();
        part[t] = v + u;
        __syncthreads();
    }
    int bx = (t > 0) ? part[t - 1] : 0;
    #pragma unroll
    for (int i = 0; i < 8; ++i) { off[base + i] = bx + loc[i]; cur[base + i] = bx + loc[i]; }
    if (t == 0) off[NN] = part[1023];
}

__global__ void scatter_kernel(const int* __restrict__ src, const int* __restrict__ dst,
                               int* __restrict__ cur, int* __restrict__ ssrc,
                               int* __restrict__ sdst) {
    int e = blockIdx.x * 256 + threadIdx.x;
    if (e < EE) {
        int d = dst[e];
        int p = atomicAdd(&cur[d], 1);
        ssrc[p] = src[e];
        sdst[p] = d;
    }
}

// ---------------- tiled cvt+transpose: dst[n*K+k] = bf16(src[k*Nn+n]), 32x32 tiles
__global__ __launch_bounds__(256) void cvt_t_kernel(const float* __restrict__ src,
                                                    u16* __restrict__ dstp, int K,
                                                    int Nn) {
    __shared__ u16 tile[32][33];
    int bk = blockIdx.x * 32, bn = blockIdx.y * 32;
    int tx = threadIdx.x & 31, ty = threadIdx.x >> 5;  // 32 x 8
    #pragma unroll
    for (int r = 0; r < 32; r += 8)
        tile[ty + r][tx] = f2bf(src[(size_t)(bk + ty + r) * Nn + bn + tx]);
    __syncthreads();
    #pragma unroll
    for (int r = 0; r < 32; r += 8)
        dstp[(size_t)(bn + ty + r) * K + bk + tx] = tile[tx][ty + r];
}

// W1 fp32 [1024][512] -> Wcat^T bf16 [1024 rows][512]:
// rows 0..511 = (W1a - W1b)^T ; rows 512..1023 = W1b^T. K=512, Nn=1024.
__global__ __launch_bounds__(256) void cvt_w1_kernel(const float* __restrict__ W1,
                                                     u16* __restrict__ dstp) {
    __shared__ u16 tile[32][33];
    int bk = blockIdx.x * 32, bn = blockIdx.y * 32;
    int tx = threadIdx.x & 31, ty = threadIdx.x >> 5;
    #pragma unroll
    for (int r = 0; r < 32; r += 8) {
        int k = bk + ty + r, n = bn + tx;
        float v = (n < 512) ? (W1[(size_t)k * 512 + n] - W1[(size_t)(k + 512) * 512 + n])
                            : W1[(size_t)(k + 512) * 512 + (n - 512)];
        tile[ty + r][tx] = f2bf(v);
    }
    __syncthreads();
    #pragma unroll
    for (int r = 0; r < 32; r += 8)
        dstp[(size_t)(bn + ty + r) * 512 + bk + tx] = tile[tx][ty + r];
}

// ---------------- async MFMA GEMM, 128x128 tile, 256 threads (2x2 waves)
// EMODE 0: relu(acc+bias)->bf16 ; 1: acc+bias+resid->fp32 ; 2: acc->bf16 ;
// EMODE 3: acc + (col<512 ? bias[col] : 0) -> bf16   (P-GEMM, folds b1 into Pa)
template <int EMODE>
__global__ __launch_bounds__(256) void gemm_async(
    const u16* __restrict__ A, const u16* __restrict__ BT,
    const float* __restrict__ bias, const float* __restrict__ resid,
    void* __restrict__ Cout, int K, int ldc) {
    __shared__ u16 lA[128 * 64];
    __shared__ u16 lB[128 * 64];
    const int tid = threadIdx.x;
    const int lane = tid & 63, wave = tid >> 6;
    const int wm = wave & 1, wn = wave >> 1;
    const int quad = lane >> 4, lm = lane & 15;
    const int tileM = blockIdx.x, tileN = blockIdx.y;

    const int g = (lane & 7) ^ (lane >> 3);
    const u16* ap[4];
    const u16* bp[4];
    u16* lad[4];
    u16* lbd[4];
    #pragma unroll
    for (int j = 0; j < 4; ++j) {
        int seg = wave * 4 + j;
        int rA = tileM * 128 + seg * 8 + (lane >> 3);
        int rB = tileN * 128 + seg * 8 + (lane >> 3);
        ap[j] = A + (size_t)rA * K + g * 8;
        bp[j] = BT + (size_t)rB * K + g * 8;
        lad[j] = lA + seg * 512;
        lbd[j] = lB + seg * 512;
    }

    f32x4 acc[4][4];
    #pragma unroll
    for (int mt = 0; mt < 4; ++mt)
        #pragma unroll
        for (int nt = 0; nt < 4; ++nt)
            #pragma unroll
            for (int j = 0; j < 4; ++j) acc[mt][nt][j] = 0.f;

    for (int kb = 0; kb < K; kb += 64) {
        #pragma unroll
        for (int j = 0; j < 4; ++j) {
            async_cp16(ap[j], lad[j]);
            async_cp16(bp[j], lbd[j]);
            ap[j] += 64;
            bp[j] += 64;
        }
        __syncthreads();
        #pragma unroll
        for (int kk = 0; kk < 64; kk += 32) {
            bf16x8 af[4], bfr[4];
            int gbase = (kk >> 3) + quad;
            #pragma unroll
            for (int mt = 0; mt < 4; ++mt) {
                int row = wm * 64 + mt * 16 + lm;
                af[mt] = *(const bf16x8*)(lA + row * 64 + ((gbase ^ (row & 7)) << 3));
            }
            #pragma unroll
            for (int nt = 0; nt < 4; ++nt) {
                int row = wn * 64 + nt * 16 + lm;
                bfr[nt] = *(const bf16x8*)(lB + row * 64 + ((gbase ^ (row & 7)) << 3));
            }
            #pragma unroll
            for (int mt = 0; mt < 4; ++mt)
                #pragma unroll
                for (int nt = 0; nt < 4; ++nt)
                    acc[mt][nt] = __builtin_amdgcn_mfma_f32_16x16x32_bf16(
                        af[mt], bfr[nt], acc[mt][nt], 0, 0, 0);
        }
        __syncthreads();
    }
    #pragma unroll
    for (int mt = 0; mt < 4; ++mt) {
        #pragma unroll
        for (int nt = 0; nt < 4; ++nt) {
            int col = tileN * 128 + wn * 64 + nt * 16 + lm;
            float bv;
            if (EMODE == 2) bv = 0.f;
            else if (EMODE == 3) bv = (col < 512) ? bias[col] : 0.f;
            else bv = bias[col];
            #pragma unroll
            for (int j = 0; j < 4; ++j) {
                int grow = tileM * 128 + wm * 64 + mt * 16 + quad * 4 + j;
                float v = acc[mt][nt][j] + bv;
                if (EMODE == 0) {
                    ((u16*)Cout)[(size_t)grow * ldc + col] = f2bf(fmaxf(v, 0.f));
                } else if (EMODE == 1) {
                    ((float*)Cout)[(size_t)grow * ldc + col] =
                        v + resid[(size_t)grow * ldc + col];
                } else {
                    ((u16*)Cout)[(size_t)grow * ldc + col] = f2bf(v);
                }
            }
        }
    }
}

// ---------------- fused edge GEMM, tile 128 edges x 256 cols, 512 thr (8 waves,
// wave-tile 64x64). LDS 48.5KB; __launch_bounds__(512,4) caps regs at 128/wave
// (incl. 64 AGPR acc) -> 2 blocks/CU co-resident: one block's waves cover the
// other's barrier drain (m114). Per kb: A-gathers issued FIRST, B
// global_load_lds second -> combine's implicit wait is vmcnt(4), B stays in
// flight until the __syncthreads. No register prefetch (costs 16 VGPR -> would
// drop to 1 block/CU, round-5 lesson).
__global__ __launch_bounds__(512, 4) void gemm_edge(
    const u16* __restrict__ P, const int* __restrict__ ssrc,
    const int* __restrict__ sdst, const u16* __restrict__ W2T,
    const float* __restrict__ b2, float* __restrict__ agg) {
    __shared__ u16 smem[128 * 64 + 256 * 64];  // lA 16KB + lB 32KB
    __shared__ int nid_l[128];
    u16* lA = smem;
    u16* lB = smem + 128 * 64;
    const int tid = threadIdx.x;
    const int lane = tid & 63, wave = tid >> 6;  // 8 waves
    const int wm = wave & 1, wn = wave >> 1;     // wave tile 64(M) x 64(N)
    const int quad = lane >> 4, lm = lane & 15;
    const int tileN = blockIdx.x;                // 0..1  (col half)
    const int ebase = blockIdx.y * 128;

    if (tid < 128) nid_l[tid] = sdst[ebase + tid];

    const int g = (lane & 7) ^ (lane >> 3);
    // A staging: 2 segments of 8 rows each; 32-bit element offsets from P
    int aoff[2], boff[2];
    u16* lout[2];
    #pragma unroll
    for (int j = 0; j < 2; ++j) {
        int seg = wave * 2 + j;
        int row = seg * 8 + (lane >> 3);
        int dn = sdst[ebase + row];
        int sn = ssrc[ebase + row];
        aoff[j] = dn * 1024 + g * 8;
        boff[j] = sn * 1024 + 512 + g * 8;
        lout[j] = lA + seg * 512 + lane * 8;
    }
    // B async staging: 4 segments of 8 rows per wave; offsets from W2T
    int woff[4];
    u16* lbd[4];
    #pragma unroll
    for (int j = 0; j < 4; ++j) {
        int seg = wave * 4 + j;  // 0..31
        int row = tileN * 256 + seg * 8 + (lane >> 3);
        woff[j] = row * 512 + g * 8;
        lbd[j] = lB + seg * 512;
    }

    f32x4 acc[4][4];
    #pragma unroll
    for (int mt = 0; mt < 4; ++mt)
        #pragma unroll
        for (int nt = 0; nt < 4; ++nt)
            #pragma unroll
            for (int j = 0; j < 4; ++j) acc[mt][nt][j] = 0.f;

    for (int kb = 0; kb < 512; kb += 64) {
        // A gathers first (oldest in vmcnt order)...
        u16x8 ga[2], gb[2];
        #pragma unroll
        for (int j = 0; j < 2; ++j) {
            ga[j] = *(const u16x8*)(P + aoff[j] + kb);
            gb[j] = *(const u16x8*)(P + boff[j] + kb);
        }
        // ...then B async copies (stay in flight while combine waits on gathers)
        #pragma unroll
        for (int j = 0; j < 4; ++j) async_cp16(W2T + woff[j] + kb, lbd[j]);
        // combine: t = relu(Pa' + Pb), pack round-half-up
        #pragma unroll
        for (int j = 0; j < 2; ++j) {
            union { u16x8 v; unsigned w[4]; } ua, ub;
            ua.v = ga[j];
            ub.v = gb[j];
            unsigned o[4];
            #pragma unroll
            for (int q = 0; q < 4; ++q) {
                float a0 = __uint_as_float(ua.w[q] << 16);
                float a1 = __uint_as_float(ua.w[q] & 0xffff0000u);
                float c0 = __uint_as_float(ub.w[q] << 16);
                float c1 = __uint_as_float(ub.w[q] & 0xffff0000u);
                float s0 = fmaxf(a0 + c0, 0.f);
                float s1 = fmaxf(a1 + c1, 0.f);
                unsigned r0 = __float_as_uint(s0) + 0x8000u;
                unsigned r1 = __float_as_uint(s1) + 0x8000u;
                o[q] = (r0 >> 16) | (r1 & 0xffff0000u);
            }
            *(uint4*)lout[j] = make_uint4(o[0], o[1], o[2], o[3]);
        }
        __syncthreads();
        #pragma unroll
        for (int kk = 0; kk < 64; kk += 32) {
            bf16x8 af[4], bfr[4];
            int gbase = (kk >> 3) + quad;
            #pragma unroll
            for (int mt = 0; mt < 4; ++mt) {
                int row = wm * 64 + mt * 16 + lm;
                af[mt] = *(const bf16x8*)(lA + row * 64 + ((gbase ^ (row & 7)) << 3));
            }
            #pragma unroll
            for (int nt = 0; nt < 4; ++nt) {
                int row = wn * 64 + nt * 16 + lm;
                bfr[nt] = *(const bf16x8*)(lB + row * 64 + ((gbase ^ (row & 7)) << 3));
            }
            #pragma unroll
            for (int mt = 0; mt < 4; ++mt)
                #pragma unroll
                for (int nt = 0; nt < 4; ++nt)
                    acc[mt][nt] = __builtin_amdgcn_mfma_f32_16x16x32_bf16(
                        af[mt], bfr[nt], acc[mt][nt], 0, 0, 0);
        }
        __syncthreads();
    }

    // epilogue: 2 passes of 64 rows; cbuf 64 x 264 (33.8KB, aliases lA/lB)
    u16* cbuf = smem;
    for (int p = 0; p < 2; ++p) {
        if (wm == p) {
            #pragma unroll
            for (int nt = 0; nt < 4; ++nt) {
                int lcol = wn * 64 + nt * 16 + lm;
                float bv = b2[tileN * 256 + lcol];
                #pragma unroll
                for (int mt = 0; mt < 4; ++mt) {
                    #pragma unroll
                    for (int j2 = 0; j2 < 4; ++j2) {
                        int row = mt * 16 + quad * 4 + j2;  // 0..63 within pass
                        cbuf[row * 264 + lcol] = f2bf(fmaxf(acc[mt][nt][j2] + bv, 0.f));
                    }
                }
            }
        }
        __syncthreads();
        {
            int lcol = tid & 255;
            int gcol = tileN * 256 + lcol;
            int r0 = (tid >> 8) * 32;  // 0 or 32 within the 64-row pass
            int gr0 = p * 64 + r0;     // row within the 128-edge tile
            int cur = nid_l[gr0];
            float run = bf2f(cbuf[r0 * 264 + lcol]);
            for (int r = 1; r < 32; ++r) {
                int nd = nid_l[gr0 + r];
                float v = bf2f(cbuf[(r0 + r) * 264 + lcol]);
                if (nd != cur) {
                    atomicMax((unsigned int*)&agg[(size_t)cur * DD + gcol],
                              __float_as_uint(run));
                    cur = nd;
                    run = v;
                } else {
                    run = fmaxf(run, v);
                }
            }
            atomicMax((unsigned int*)&agg[(size_t)cur * DD + gcol],
                      __float_as_uint(run));
        }
        __syncthreads();
    }
}

// ---------------- gather selected rows with residual add: xs[i] = x[r] + agg[r]
__global__ __launch_bounds__(128) void gather_fused(const float* __restrict__ x,
                                                    const float* __restrict__ agg,
                                                    const int* __restrict__ sel,
                                                    float* __restrict__ xs) {
    int i = blockIdx.x;
    int b = i >> 7;
    int r = b * NPG + sel[i];
    const f32x4* srcp = (const f32x4*)(x + (size_t)r * DD);
    const f32x4* aggp = (const f32x4*)(agg + (size_t)r * DD);
    f32x4 v = srcp[threadIdx.x];
    f32x4 a = aggp[threadIdx.x];
    #pragma unroll
    for (int j = 0; j < 4; ++j) v[j] += a[j];
    ((f32x4*)(xs + (size_t)i * DD))[threadIdx.x] = v;
}

extern "C" void kernel_launch(void* const* d_in, const int* in_sizes, int n_in,
                              void* d_out, int out_size, void* d_ws, size_t ws_size,
                              hipStream_t stream) {
    const float* x_in = (const float*)d_in[0];
    const int* ei = (const int*)d_in[1];
    const int* sel = (const int*)d_in[2];
    const float* W1 = (const float*)d_in[4];
    const float* b1 = (const float*)d_in[5];
    const float* W2 = (const float*)d_in[6];
    const float* b2 = (const float*)d_in[7];
    const float* g1 = (const float*)d_in[8];
    const float* be1 = (const float*)d_in[9];
    const float* g2 = (const float*)d_in[10];
    const float* be2 = (const float*)d_in[11];
    const float* fW1 = (const float*)d_in[12];
    const float* fb1 = (const float*)d_in[13];
    const float* fW2 = (const float*)d_in[14];
    const float* fb2 = (const float*)d_in[15];
    float* out = (float*)d_out;

    char* w = (char*)d_ws;
    size_t off = 0;
    auto alloc = [&](size_t bytes) -> char* {
        char* p = w + off;
        off += (bytes + 255) & ~(size_t)255;
        return p;
    };
    float* xbuf = (float*)alloc((size_t)NN * DD * 4);
    float* agg  = (float*)alloc((size_t)NN * DD * 4);
    u16* h      = (u16*)alloc((size_t)NN * DD * 2);
    u16* P      = (u16*)alloc((size_t)NN * 1024 * 2);
    u16* W1T    = (u16*)alloc((size_t)LL * 1024 * DD * 2);
    u16* W2T    = (u16*)alloc((size_t)LL * DD * DD * 2);
    u16* FW1T   = (u16*)alloc((size_t)DD * DD * 2);
    u16* FW2T   = (u16*)alloc((size_t)DD * DD * 2);
    int* cnt    = (int*)alloc((size_t)NN * 4);
    int* offs   = (int*)alloc((size_t)(NN + 1) * 4);
    int* cur    = (int*)alloc((size_t)NN * 4);
    int* ssrc   = (int*)alloc((size_t)EE * 4);
    int* sdst   = (int*)alloc((size_t)EE * 4);
    float* xs   = (float*)alloc((size_t)BBATCH * SSEL * DD * 4);
    u16* hs     = (u16*)alloc((size_t)BBATCH * SSEL * DD * 2);
    u16* uu     = (u16*)alloc((size_t)BBATCH * SSEL * DD * 2);

    const int* esrc = ei;       // edge_index[0] = x_j
    const int* edst = ei + EE;  // edge_index[1] = x_i / aggregation index

    hipMemsetAsync(cnt, 0, (size_t)NN * 4, stream);
    hist_kernel<<<EE / 256, 256, 0, stream>>>(edst, cnt);
    scan_kernel<<<1, 1024, 0, stream>>>(cnt, offs, cur);
    scatter_kernel<<<EE / 256, 256, 0, stream>>>(esrc, edst, cur, ssrc, sdst);

    for (int l = 0; l < LL; ++l) {
        cvt_w1_kernel<<<dim3(16, 32), 256, 0, stream>>>(
            W1 + (size_t)l * 1024 * DD, W1T + (size_t)l * 1024 * DD);
        cvt_t_kernel<<<dim3(16, 16), 256, 0, stream>>>(
            W2 + (size_t)l * DD * DD, W2T + (size_t)l * DD * DD, DD, DD);
    }
    cvt_t_kernel<<<dim3(16, 16), 256, 0, stream>>>(fW1, FW1T, DD, DD);
    cvt_t_kernel<<<dim3(16, 16), 256, 0, stream>>>(fW2, FW2T, DD, DD);

    for (int l = 0; l < LL; ++l) {
        // x_l = x_{l-1} + agg ; h = LN(x_l) ; agg <- 0 for this layer's atomics
        ln_fused<<<NN, 64, 0, stream>>>(l == 0 ? x_in : xbuf, agg, xbuf, g1, be1, h,
                                        l > 0 ? 1 : 0);
        // P = h @ [W1a-W1b | W1b] + [b1 | 0]   [8192 x 1024] bf16
        {
            dim3 grid(NN / 128, 1024 / 128);
            gemm_async<3><<<grid, 256, 0, stream>>>(
                h, W1T + (size_t)l * 1024 * DD, b1 + (size_t)l * DD, nullptr, P, DD,
                1024);
        }
        // fused: edge-combine + GEMM2 + relu + segmax-atomics into agg
        gemm_edge<<<dim3(2, EE / 128), 512, 0, stream>>>(
            P, ssrc, sdst, W2T + (size_t)l * DD * DD, b2 + (size_t)l * DD, agg);
    }

    gather_fused<<<BBATCH * SSEL, 128, 0, stream>>>(xbuf, agg, sel, xs);
    ln_fused<<<BBATCH * SSEL, 64, 0, stream>>>(xs, nullptr, xs, g2, be2, hs, 0);
    dim3 gridf(BBATCH * SSEL / 128, DD / 128);
    gemm_async<0><<<gridf, 256, 0, stream>>>(hs, FW1T, fb1, nullptr, uu, DD, DD);
    gemm_async<1><<<gridf, 256, 0, stream>>>(uu, FW2T, fb2, xs, out, DD, DD);
}

// Round 7
// 548.409 us; speedup vs baseline: 4.0652x; 1.1309x over previous
//
#include <hip/hip_runtime.h>
#include <stdint.h>

#define NN 8192
#define DD 512
#define EE 131072
#define BBATCH 16
#define NPG 512
#define SSEL 128
#define LL 3

typedef unsigned short u16;
typedef __bf16 bf16x8 __attribute__((ext_vector_type(8)));
typedef float f32x4 __attribute__((ext_vector_type(4)));
typedef float f32x2 __attribute__((ext_vector_type(2)));
typedef u16 u16x8 __attribute__((ext_vector_type(8)));

__device__ __forceinline__ float bf2f(u16 u) {
    union { unsigned i; float f; } v; v.i = ((unsigned)u) << 16; return v.f;
}
__device__ __forceinline__ u16 f2bf(float f) {
    union { unsigned i; float f; } v; v.f = f;
    unsigned i = v.i;
    return (u16)((i + 0x7FFFu + ((i >> 16) & 1u)) >> 16);  // RNE
}

// pack two fp32 -> packed bf16x2 in one uint (lo = s0, hi = s1)
__device__ __forceinline__ unsigned pk_bf16(float s0, float s1) {
#if __has_builtin(__builtin_amdgcn_cvt_pk_bf16_f32)
    typedef __bf16 bf16x2 __attribute__((ext_vector_type(2)));
    union { bf16x2 v; unsigned u; } r;
    r.v = __builtin_amdgcn_cvt_pk_bf16_f32(s0, s1);
    return r.u;
#else
    unsigned r0 = __float_as_uint(s0);
    r0 = (r0 + 0x7FFFu + ((r0 >> 16) & 1u)) >> 16;
    unsigned r1 = __float_as_uint(s1);
    r1 = (r1 + 0x7FFFu + ((r1 >> 16) & 1u)) & 0xffff0000u;
    return r0 | r1;
#endif
}

// async global->LDS, 16B per lane, LDS dest = wave-uniform base + lane*16
__device__ __forceinline__ void async_cp16(const u16* g, u16* l) {
    __builtin_amdgcn_global_load_lds(
        (const __attribute__((address_space(1))) unsigned int*)g,
        (__attribute__((address_space(3))) unsigned int*)l, 16, 0, 0);
}

// ---------------- LayerNorm (+ optional residual-add + agg zeroing)
// 4 rows per 256-thr block (wave per row)
__global__ __launch_bounds__(256) void ln_fused(const float* __restrict__ xin,
                                                float* __restrict__ agg_io,
                                                float* __restrict__ xout,
                                                const float* __restrict__ g,
                                                const float* __restrict__ b,
                                                u16* __restrict__ h, int doAdd) {
    int row = blockIdx.x * 4 + (threadIdx.x >> 6);
    int lane = threadIdx.x & 63;
    const f32x4* x4 = (const f32x4*)(xin + (size_t)row * DD);
    f32x4 p = x4[lane * 2], q = x4[lane * 2 + 1];
    if (doAdd) {
        const f32x4* a4 = (const f32x4*)(agg_io + (size_t)row * DD);
        f32x4 pa = a4[lane * 2], qa = a4[lane * 2 + 1];
        #pragma unroll
        for (int i = 0; i < 4; ++i) { p[i] += pa[i]; q[i] += qa[i]; }
    }
    if (agg_io) {
        f32x4 z;
        #pragma unroll
        for (int i = 0; i < 4; ++i) z[i] = 0.f;
        f32x4* a4 = (f32x4*)(agg_io + (size_t)row * DD);
        a4[lane * 2] = z;
        a4[lane * 2 + 1] = z;
    }
    f32x4* xo = (f32x4*)(xout + (size_t)row * DD);
    xo[lane * 2] = p;
    xo[lane * 2 + 1] = q;
    float v[8];
    v[0] = p[0]; v[1] = p[1]; v[2] = p[2]; v[3] = p[3];
    v[4] = q[0]; v[5] = q[1]; v[6] = q[2]; v[7] = q[3];
    float s = 0.f, sq = 0.f;
    #pragma unroll
    for (int i = 0; i < 8; ++i) { s += v[i]; sq += v[i] * v[i]; }
    #pragma unroll
    for (int o = 32; o >= 1; o >>= 1) { s += __shfl_xor(s, o); sq += __shfl_xor(sq, o); }
    float mu = s * (1.f / DD);
    float var = sq * (1.f / DD) - mu * mu;
    float rs = rsqrtf(var + 1e-5f);
    int kb = lane * 8;
    u16x8 o8;
    #pragma unroll
    for (int i = 0; i < 8; ++i) o8[i] = f2bf((v[i] - mu) * rs * g[kb + i] + b[kb + i]);
    *(u16x8*)(h + (size_t)row * DD + kb) = o8;
}

// ---------------- counting sort by dst
__global__ void hist_kernel(const int* __restrict__ dst, int* __restrict__ cnt) {
    int e = blockIdx.x * 256 + threadIdx.x;
    if (e < EE) atomicAdd(&cnt[dst[e]], 1);
}

__global__ __launch_bounds__(1024) void scan_kernel(const int* __restrict__ cnt,
                                                    int* __restrict__ off,
                                                    int* __restrict__ cur) {
    __shared__ int part[1024];
    int t = threadIdx.x;
    int base = t * 8;
    int loc[8]; int s = 0;
    #pragma unroll
    for (int i = 0; i < 8; ++i) { loc[i] = s; s += cnt[base + i]; }
    part[t] = s;
    __syncthreads();
    for (int o = 1; o < 1024; o <<= 1) {
        int v = part[t];
        int u = (t >= o) ? part[t - o] : 0;
        __syncthreads();
        part[t] = v + u;
        __syncthreads();
    }
    int bx = (t > 0) ? part[t - 1] : 0;
    #pragma unroll
    for (int i = 0; i < 8; ++i) { off[base + i] = bx + loc[i]; cur[base + i] = bx + loc[i]; }
    if (t == 0) off[NN] = part[1023];
}

__global__ void scatter_kernel(const int* __restrict__ src, const int* __restrict__ dst,
                               int* __restrict__ cur, int* __restrict__ ssrc,
                               int* __restrict__ sdst) {
    int e = blockIdx.x * 256 + threadIdx.x;
    if (e < EE) {
        int d = dst[e];
        int p = atomicAdd(&cur[d], 1);
        ssrc[p] = src[e];
        sdst[p] = d;
    }
}

// ---------------- 5x fused cvt+transpose for 512x512 fp32 mats -> bf16 [N][K]
struct CvtJobs {
    const float* s[5];
    u16* d[5];
};
__global__ __launch_bounds__(256) void cvt_t5_kernel(CvtJobs jobs) {
    __shared__ u16 tile[32][33];
    const float* src = jobs.s[blockIdx.z];
    u16* dstp = jobs.d[blockIdx.z];
    int bk = blockIdx.x * 32, bn = blockIdx.y * 32;
    int tx = threadIdx.x & 31, ty = threadIdx.x >> 5;  // 32 x 8
    #pragma unroll
    for (int r = 0; r < 32; r += 8)
        tile[ty + r][tx] = f2bf(src[(size_t)(bk + ty + r) * 512 + bn + tx]);
    __syncthreads();
    #pragma unroll
    for (int r = 0; r < 32; r += 8)
        dstp[(size_t)(bn + ty + r) * 512 + bk + tx] = tile[tx][ty + r];
}

// W1 fp32 [L][1024][512] -> Wcat^T bf16 [L][1024 rows][512]:
// rows 0..511 = (W1a - W1b)^T ; rows 512..1023 = W1b^T. z = layer.
__global__ __launch_bounds__(256) void cvt_w1_kernel(const float* __restrict__ W1g,
                                                     u16* __restrict__ dstg) {
    __shared__ u16 tile[32][33];
    const float* W1 = W1g + (size_t)blockIdx.z * 1024 * 512;
    u16* dstp = dstg + (size_t)blockIdx.z * 1024 * 512;
    int bk = blockIdx.x * 32, bn = blockIdx.y * 32;
    int tx = threadIdx.x & 31, ty = threadIdx.x >> 5;
    #pragma unroll
    for (int r = 0; r < 32; r += 8) {
        int k = bk + ty + r, n = bn + tx;
        float v = (n < 512) ? (W1[(size_t)k * 512 + n] - W1[(size_t)(k + 512) * 512 + n])
                            : W1[(size_t)(k + 512) * 512 + (n - 512)];
        tile[ty + r][tx] = f2bf(v);
    }
    __syncthreads();
    #pragma unroll
    for (int r = 0; r < 32; r += 8)
        dstp[(size_t)(bn + ty + r) * 512 + bk + tx] = tile[tx][ty + r];
}

// ---------------- async MFMA GEMM, 128x128 tile, 256 threads (2x2 waves)
// EMODE 0: relu(acc+bias)->bf16 ; 1: acc+bias+resid->fp32 ; 2: acc->bf16 ;
// EMODE 3: acc + (col<512 ? bias[col] : 0) -> bf16   (P-GEMM, folds b1 into Pa)
template <int EMODE>
__global__ __launch_bounds__(256) void gemm_async(
    const u16* __restrict__ A, const u16* __restrict__ BT,
    const float* __restrict__ bias, const float* __restrict__ resid,
    void* __restrict__ Cout, int K, int ldc) {
    __shared__ u16 lA[128 * 64];
    __shared__ u16 lB[128 * 64];
    const int tid = threadIdx.x;
    const int lane = tid & 63, wave = tid >> 6;
    const int wm = wave & 1, wn = wave >> 1;
    const int quad = lane >> 4, lm = lane & 15;
    const int tileM = blockIdx.x, tileN = blockIdx.y;

    const int g = (lane & 7) ^ (lane >> 3);
    const u16* ap[4];
    const u16* bp[4];
    u16* lad[4];
    u16* lbd[4];
    #pragma unroll
    for (int j = 0; j < 4; ++j) {
        int seg = wave * 4 + j;
        int rA = tileM * 128 + seg * 8 + (lane >> 3);
        int rB = tileN * 128 + seg * 8 + (lane >> 3);
        ap[j] = A + (size_t)rA * K + g * 8;
        bp[j] = BT + (size_t)rB * K + g * 8;
        lad[j] = lA + seg * 512;
        lbd[j] = lB + seg * 512;
    }

    f32x4 acc[4][4];
    #pragma unroll
    for (int mt = 0; mt < 4; ++mt)
        #pragma unroll
        for (int nt = 0; nt < 4; ++nt)
            #pragma unroll
            for (int j = 0; j < 4; ++j) acc[mt][nt][j] = 0.f;

    for (int kb = 0; kb < K; kb += 64) {
        #pragma unroll
        for (int j = 0; j < 4; ++j) {
            async_cp16(ap[j], lad[j]);
            async_cp16(bp[j], lbd[j]);
            ap[j] += 64;
            bp[j] += 64;
        }
        __syncthreads();
        #pragma unroll
        for (int kk = 0; kk < 64; kk += 32) {
            bf16x8 af[4], bfr[4];
            int gbase = (kk >> 3) + quad;
            #pragma unroll
            for (int mt = 0; mt < 4; ++mt) {
                int row = wm * 64 + mt * 16 + lm;
                af[mt] = *(const bf16x8*)(lA + row * 64 + ((gbase ^ (row & 7)) << 3));
            }
            #pragma unroll
            for (int nt = 0; nt < 4; ++nt) {
                int row = wn * 64 + nt * 16 + lm;
                bfr[nt] = *(const bf16x8*)(lB + row * 64 + ((gbase ^ (row & 7)) << 3));
            }
            #pragma unroll
            for (int mt = 0; mt < 4; ++mt)
                #pragma unroll
                for (int nt = 0; nt < 4; ++nt)
                    acc[mt][nt] = __builtin_amdgcn_mfma_f32_16x16x32_bf16(
                        af[mt], bfr[nt], acc[mt][nt], 0, 0, 0);
        }
        __syncthreads();
    }
    #pragma unroll
    for (int mt = 0; mt < 4; ++mt) {
        #pragma unroll
        for (int nt = 0; nt < 4; ++nt) {
            int col = tileN * 128 + wn * 64 + nt * 16 + lm;
            float bv;
            if (EMODE == 2) bv = 0.f;
            else if (EMODE == 3) bv = (col < 512) ? bias[col] : 0.f;
            else bv = bias[col];
            #pragma unroll
            for (int j = 0; j < 4; ++j) {
                int grow = tileM * 128 + wm * 64 + mt * 16 + quad * 4 + j;
                float v = acc[mt][nt][j] + bv;
                if (EMODE == 0) {
                    ((u16*)Cout)[(size_t)grow * ldc + col] = f2bf(fmaxf(v, 0.f));
                } else if (EMODE == 1) {
                    ((float*)Cout)[(size_t)grow * ldc + col] =
                        v + resid[(size_t)grow * ldc + col];
                } else {
                    ((u16*)Cout)[(size_t)grow * ldc + col] = f2bf(v);
                }
            }
        }
    }
}

// ---------------- fused edge GEMM, tile 128 edges x 256 cols, 512 thr (8 waves,
// wave-tile 64x64). LDS 48.5KB; launch_bounds(512,4) caps regs at 128/wave
// (incl. 64 AGPR acc) -> 2 blocks/CU co-resident (round-6 lesson: any more
// VGPRs drops a whole block). Combine uses packed math: v_pk_add_f32 /
// v_pk_max_f32 / v_cvt_pk_bf16_f32 (round-7: halves combine VALU).
__global__ __launch_bounds__(512, 4) void gemm_edge(
    const u16* __restrict__ P, const int* __restrict__ ssrc,
    const int* __restrict__ sdst, const u16* __restrict__ W2T,
    const float* __restrict__ b2, float* __restrict__ agg) {
    __shared__ u16 smem[128 * 64 + 256 * 64];  // lA 16KB + lB 32KB
    __shared__ int nid_l[128];
    u16* lA = smem;
    u16* lB = smem + 128 * 64;
    const int tid = threadIdx.x;
    const int lane = tid & 63, wave = tid >> 6;  // 8 waves
    const int wm = wave & 1, wn = wave >> 1;     // wave tile 64(M) x 64(N)
    const int quad = lane >> 4, lm = lane & 15;
    const int tileN = blockIdx.x;                // 0..1  (col half)
    const int ebase = blockIdx.y * 128;

    if (tid < 128) nid_l[tid] = sdst[ebase + tid];

    const int g = (lane & 7) ^ (lane >> 3);
    // A staging: 2 segments of 8 rows each; 32-bit element offsets from P
    int aoff[2], boff[2];
    u16* lout[2];
    #pragma unroll
    for (int j = 0; j < 2; ++j) {
        int seg = wave * 2 + j;
        int row = seg * 8 + (lane >> 3);
        int dn = sdst[ebase + row];
        int sn = ssrc[ebase + row];
        aoff[j] = dn * 1024 + g * 8;
        boff[j] = sn * 1024 + 512 + g * 8;
        lout[j] = lA + seg * 512 + lane * 8;
    }
    // B async staging: 4 segments of 8 rows per wave; offsets from W2T
    int woff[4];
    u16* lbd[4];
    #pragma unroll
    for (int j = 0; j < 4; ++j) {
        int seg = wave * 4 + j;  // 0..31
        int row = tileN * 256 + seg * 8 + (lane >> 3);
        woff[j] = row * 512 + g * 8;
        lbd[j] = lB + seg * 512;
    }

    f32x4 acc[4][4];
    #pragma unroll
    for (int mt = 0; mt < 4; ++mt)
        #pragma unroll
        for (int nt = 0; nt < 4; ++nt)
            #pragma unroll
            for (int j = 0; j < 4; ++j) acc[mt][nt][j] = 0.f;

    for (int kb = 0; kb < 512; kb += 64) {
        // A gathers first (oldest in vmcnt order)...
        u16x8 ga[2], gb[2];
        #pragma unroll
        for (int j = 0; j < 2; ++j) {
            ga[j] = *(const u16x8*)(P + aoff[j] + kb);
            gb[j] = *(const u16x8*)(P + boff[j] + kb);
        }
        // ...then B async copies (stay in flight while combine waits on gathers)
        #pragma unroll
        for (int j = 0; j < 4; ++j) async_cp16(W2T + woff[j] + kb, lbd[j]);
        // combine: t = relu(Pa' + Pb), packed math
        #pragma unroll
        for (int j = 0; j < 2; ++j) {
            union { u16x8 v; unsigned w[4]; } ua, ub;
            ua.v = ga[j];
            ub.v = gb[j];
            unsigned o[4];
            #pragma unroll
            for (int q = 0; q < 4; ++q) {
                f32x2 a, c;
                a[0] = __uint_as_float(ua.w[q] << 16);
                a[1] = __uint_as_float(ua.w[q] & 0xffff0000u);
                c[0] = __uint_as_float(ub.w[q] << 16);
                c[1] = __uint_as_float(ub.w[q] & 0xffff0000u);
                f32x2 s = a + c;
#if __has_builtin(__builtin_elementwise_max)
                f32x2 z; z[0] = 0.f; z[1] = 0.f;
                s = __builtin_elementwise_max(s, z);
#else
                s[0] = fmaxf(s[0], 0.f);
                s[1] = fmaxf(s[1], 0.f);
#endif
                o[q] = pk_bf16(s[0], s[1]);
            }
            *(uint4*)lout[j] = make_uint4(o[0], o[1], o[2], o[3]);
        }
        __syncthreads();
        #pragma unroll
        for (int kk = 0; kk < 64; kk += 32) {
            bf16x8 af[4], bfr[4];
            int gbase = (kk >> 3) + quad;
            #pragma unroll
            for (int mt = 0; mt < 4; ++mt) {
                int row = wm * 64 + mt * 16 + lm;
                af[mt] = *(const bf16x8*)(lA + row * 64 + ((gbase ^ (row & 7)) << 3));
            }
            #pragma unroll
            for (int nt = 0; nt < 4; ++nt) {
                int row = wn * 64 + nt * 16 + lm;
                bfr[nt] = *(const bf16x8*)(lB + row * 64 + ((gbase ^ (row & 7)) << 3));
            }
            #pragma unroll
            for (int mt = 0; mt < 4; ++mt)
                #pragma unroll
                for (int nt = 0; nt < 4; ++nt)
                    acc[mt][nt] = __builtin_amdgcn_mfma_f32_16x16x32_bf16(
                        af[mt], bfr[nt], acc[mt][nt], 0, 0, 0);
        }
        __syncthreads();
    }

    // epilogue: 2 passes of 64 rows; cbuf 64 x 264 (33.8KB, aliases lA/lB)
    u16* cbuf = smem;
    for (int p = 0; p < 2; ++p) {
        if (wm == p) {
            #pragma unroll
            for (int nt = 0; nt < 4; ++nt) {
                int lcol = wn * 64 + nt * 16 + lm;
                float bv = b2[tileN * 256 + lcol];
                #pragma unroll
                for (int mt = 0; mt < 4; ++mt) {
                    #pragma unroll
                    for (int j2 = 0; j2 < 4; ++j2) {
                        int row = mt * 16 + quad * 4 + j2;  // 0..63 within pass
                        cbuf[row * 264 + lcol] = f2bf(fmaxf(acc[mt][nt][j2] + bv, 0.f));
                    }
                }
            }
        }
        __syncthreads();
        {
            int lcol = tid & 255;
            int gcol = tileN * 256 + lcol;
            int r0 = (tid >> 8) * 32;  // 0 or 32 within the 64-row pass
            int gr0 = p * 64 + r0;     // row within the 128-edge tile
            int cur = nid_l[gr0];
            float run = bf2f(cbuf[r0 * 264 + lcol]);
            for (int r = 1; r < 32; ++r) {
                int nd = nid_l[gr0 + r];
                float v = bf2f(cbuf[(r0 + r) * 264 + lcol]);
                if (nd != cur) {
                    atomicMax((unsigned int*)&agg[(size_t)cur * DD + gcol],
                              __float_as_uint(run));
                    cur = nd;
                    run = v;
                } else {
                    run = fmaxf(run, v);
                }
            }
            atomicMax((unsigned int*)&agg[(size_t)cur * DD + gcol],
                      __float_as_uint(run));
        }
        __syncthreads();
    }
}

// ---------------- gather selected rows with residual add: xs[i] = x[r] + agg[r]
__global__ __launch_bounds__(128) void gather_fused(const float* __restrict__ x,
                                                    const float* __restrict__ agg,
                                                    const int* __restrict__ sel,
                                                    float* __restrict__ xs) {
    int i = blockIdx.x;
    int b = i >> 7;
    int r = b * NPG + sel[i];
    const f32x4* srcp = (const f32x4*)(x + (size_t)r * DD);
    const f32x4* aggp = (const f32x4*)(agg + (size_t)r * DD);
    f32x4 v = srcp[threadIdx.x];
    f32x4 a = aggp[threadIdx.x];
    #pragma unroll
    for (int j = 0; j < 4; ++j) v[j] += a[j];
    ((f32x4*)(xs + (size_t)i * DD))[threadIdx.x] = v;
}

extern "C" void kernel_launch(void* const* d_in, const int* in_sizes, int n_in,
                              void* d_out, int out_size, void* d_ws, size_t ws_size,
                              hipStream_t stream) {
    const float* x_in = (const float*)d_in[0];
    const int* ei = (const int*)d_in[1];
    const int* sel = (const int*)d_in[2];
    const float* W1 = (const float*)d_in[4];
    const float* b1 = (const float*)d_in[5];
    const float* W2 = (const float*)d_in[6];
    const float* b2 = (const float*)d_in[7];
    const float* g1 = (const float*)d_in[8];
    const float* be1 = (const float*)d_in[9];
    const float* g2 = (const float*)d_in[10];
    const float* be2 = (const float*)d_in[11];
    const float* fW1 = (const float*)d_in[12];
    const float* fb1 = (const float*)d_in[13];
    const float* fW2 = (const float*)d_in[14];
    const float* fb2 = (const float*)d_in[15];
    float* out = (float*)d_out;

    char* w = (char*)d_ws;
    size_t off = 0;
    auto alloc = [&](size_t bytes) -> char* {
        char* p = w + off;
        off += (bytes + 255) & ~(size_t)255;
        return p;
    };
    float* xbuf = (float*)alloc((size_t)NN * DD * 4);
    float* agg  = (float*)alloc((size_t)NN * DD * 4);
    u16* h      = (u16*)alloc((size_t)NN * DD * 2);
    u16* P      = (u16*)alloc((size_t)NN * 1024 * 2);
    u16* W1T    = (u16*)alloc((size_t)LL * 1024 * DD * 2);
    u16* W2T    = (u16*)alloc((size_t)LL * DD * DD * 2);
    u16* FW1T   = (u16*)alloc((size_t)DD * DD * 2);
    u16* FW2T   = (u16*)alloc((size_t)DD * DD * 2);
    int* cnt    = (int*)alloc((size_t)NN * 4);
    int* offs   = (int*)alloc((size_t)(NN + 1) * 4);
    int* cur    = (int*)alloc((size_t)NN * 4);
    int* ssrc   = (int*)alloc((size_t)EE * 4);
    int* sdst   = (int*)alloc((size_t)EE * 4);
    float* xs   = (float*)alloc((size_t)BBATCH * SSEL * DD * 4);
    u16* hs     = (u16*)alloc((size_t)BBATCH * SSEL * DD * 2);
    u16* uu     = (u16*)alloc((size_t)BBATCH * SSEL * DD * 2);

    const int* esrc = ei;       // edge_index[0] = x_j
    const int* edst = ei + EE;  // edge_index[1] = x_i / aggregation index

    hipMemsetAsync(cnt, 0, (size_t)NN * 4, stream);
    hist_kernel<<<EE / 256, 256, 0, stream>>>(edst, cnt);
    scan_kernel<<<1, 1024, 0, stream>>>(cnt, offs, cur);
    scatter_kernel<<<EE / 256, 256, 0, stream>>>(esrc, edst, cur, ssrc, sdst);

    // all weight conversions in 2 launches
    cvt_w1_kernel<<<dim3(16, 32, LL), 256, 0, stream>>>(W1, W1T);
    {
        CvtJobs jobs;
        jobs.s[0] = W2;
        jobs.s[1] = W2 + (size_t)DD * DD;
        jobs.s[2] = W2 + (size_t)2 * DD * DD;
        jobs.s[3] = fW1;
        jobs.s[4] = fW2;
        jobs.d[0] = W2T;
        jobs.d[1] = W2T + (size_t)DD * DD;
        jobs.d[2] = W2T + (size_t)2 * DD * DD;
        jobs.d[3] = FW1T;
        jobs.d[4] = FW2T;
        cvt_t5_kernel<<<dim3(16, 16, 5), 256, 0, stream>>>(jobs);
    }

    for (int l = 0; l < LL; ++l) {
        // x_l = x_{l-1} + agg ; h = LN(x_l) ; agg <- 0 for this layer's atomics
        ln_fused<<<NN / 4, 256, 0, stream>>>(l == 0 ? x_in : xbuf, agg, xbuf, g1, be1,
                                             h, l > 0 ? 1 : 0);
        // P = h @ [W1a-W1b | W1b] + [b1 | 0]   [8192 x 1024] bf16
        {
            dim3 grid(NN / 128, 1024 / 128);
            gemm_async<3><<<grid, 256, 0, stream>>>(
                h, W1T + (size_t)l * 1024 * DD, b1 + (size_t)l * DD, nullptr, P, DD,
                1024);
        }
        // fused: edge-combine + GEMM2 + relu + segmax-atomics into agg
        gemm_edge<<<dim3(2, EE / 128), 512, 0, stream>>>(
            P, ssrc, sdst, W2T + (size_t)l * DD * DD, b2 + (size_t)l * DD, agg);
    }

    gather_fused<<<BBATCH * SSEL, 128, 0, stream>>>(xbuf, agg, sel, xs);
    ln_fused<<<BBATCH * SSEL / 4, 256, 0, stream>>>(xs, nullptr, xs, g2, be2, hs, 0);
    dim3 gridf(BBATCH * SSEL / 128, DD / 128);
    gemm_async<0><<<gridf, 256, 0, stream>>>(hs, FW1T, fb1, nullptr, uu, DD, DD);
    gemm_async<1><<<gridf, 256, 0, stream>>>(uu, FW2T, fb2, xs, out, DD, DD);
}